// Round 1
// baseline (1551.317 us; speedup 1.0000x reference)
//
#include <hip/hip_runtime.h>
#include <math.h>

#define B_TOTAL 32768
#define TB 64
#define NCH 256
#define EPS 1e-5f

// ---------------------------------------------------------------------------
// stats pass 1: sums[0..41] = sum_b x[b,i]; sums[42..1805] = sum_b x[b,i]*x[b,j]
// ---------------------------------------------------------------------------
__global__ __launch_bounds__(256) void stats1_kernel(const float* __restrict__ x,
                                                     float* __restrict__ sums) {
  __shared__ float xb[128 * 42];
  const int tid = threadIdx.x;
  const int bid = blockIdx.x;
  // load 128 boards = 5376 floats = 1344 float4 (contiguous, coalesced)
  const float4* src = (const float4*)(x + (size_t)bid * 128 * 42);
  float4* dst = (float4*)xb;
  for (int i = tid; i < 1344; i += 256) dst[i] = src[i];
  __syncthreads();
  // full 42x42 second-moment matrix (symmetric, computed dense for simplicity)
  for (int s = 0; s < 7; ++s) {
    int pidx = s * 256 + tid;
    if (pidx < 42 * 42) {
      int i = pidx / 42;
      int j = pidx - i * 42;
      float acc = 0.f;
      for (int b = 0; b < 128; ++b)
        acc = fmaf(xb[b * 42 + i], xb[b * 42 + j], acc);
      atomicAdd(&sums[42 + pidx], acc);
    }
  }
  if (tid < 42) {
    float acc = 0.f;
    for (int b = 0; b < 128; ++b) acc += xb[b * 42 + tid];
    atomicAdd(&sums[tid], acc);
  }
}

// ---------------------------------------------------------------------------
// stats pass 2: per-channel BN-affine coefficients.
//   mean[c] = cb + (1/12) sum_p w_c . m_patch(p)
//   E[y^2][c] = (1/12) sum_p (cb^2 + 2 cb (w.m_p) + w^T S_p w)
//   h = relu(A_c * dot + D_c),  A = gamma*rsqrt(var+eps), D = beta + A*(cb-mean)
// ---------------------------------------------------------------------------
__global__ __launch_bounds__(256) void stats2_kernel(
    const float* __restrict__ sums, const float* __restrict__ convw,
    const float* __restrict__ convb, const float* __restrict__ gamma,
    const float* __restrict__ beta, float* __restrict__ AD) {
  __shared__ float sM[42];
  __shared__ float sS[42 * 42];
  const int tid = threadIdx.x;
  const float invB = 1.f / (float)B_TOTAL;
  for (int i = tid; i < 42 + 42 * 42; i += 256) {
    float v = sums[i] * invB;
    if (i < 42) sM[i] = v; else sS[i - 42] = v;
  }
  __syncthreads();
  float w[16];
#pragma unroll
  for (int k = 0; k < 16; ++k) w[k] = convw[tid * 16 + k];
  const float cb = convb[tid];
  float accm = 0.f, acc2 = 0.f;
  for (int p = 0; p < 12; ++p) {
    const int pi = p >> 2, pj = p & 3;
    int idx[16];
#pragma unroll
    for (int k = 0; k < 16; ++k) idx[k] = (pi + (k >> 2)) * 7 + pj + (k & 3);
    float dm = 0.f, q = 0.f;
#pragma unroll
    for (int k = 0; k < 16; ++k) {
      dm = fmaf(w[k], sM[idx[k]], dm);
      float t = 0.f;
      const float* Srow = &sS[idx[k] * 42];
#pragma unroll
      for (int k2 = 0; k2 < 16; ++k2) t = fmaf(w[k2], Srow[idx[k2]], t);
      q = fmaf(w[k], t, q);
    }
    accm += dm;
    acc2 += cb * cb + 2.f * cb * dm + q;
  }
  const float meanY = cb + accm * (1.f / 12.f);
  const float EY2 = acc2 * (1.f / 12.f);
  float var = EY2 - meanY * meanY;
  var = fmaxf(var, 0.f);
  const float alpha = gamma[tid] * rsqrtf(var + EPS);
  AD[tid] = alpha;
  AD[NCH + tid] = beta[tid] + alpha * (cb - meanY);
}

// ---------------------------------------------------------------------------
// fused main kernel: conv + BN + relu + both heads, 64 boards per block.
// h @ [pw1|vw1] computed as sum over 256 channel-slices of (64x12)@(12x128).
// ---------------------------------------------------------------------------
struct Stage1 {
  float convw[NCH * 16];   // 16384 B
  float A[NCH];            // 1024 B
  float D[NCH];            // 1024 B
  float boards[TB * 43];   // padded stride 43 (odd) -> conflict-free
  float htile[12 * TB];    // [p][board]
  float wslice[12 * 128];  // [k][neuron]  (cols 0..63 = pw1, 64..127 = vw1)
};
struct Stage2 {
  float act[TB * 132];     // padded stride 132
  float p2v2[TB * 65];     // padded stride 65 (odd)
};
union SharedU { Stage1 s1; Stage2 s2; };

__global__ __launch_bounds__(256, 3) void fused_kernel(
    const float* __restrict__ x, const float* __restrict__ convw,
    const float* __restrict__ AD,
    const float* __restrict__ pw1, const float* __restrict__ pb1,
    const float* __restrict__ pw2, const float* __restrict__ pb2,
    const float* __restrict__ pw3, const float* __restrict__ pb3,
    const float* __restrict__ vw1, const float* __restrict__ vb1,
    const float* __restrict__ vw2, const float* __restrict__ vb2,
    const float* __restrict__ vw3, const float* __restrict__ vb3,
    float* __restrict__ out) {
  __shared__ SharedU sh;
  const int tid = threadIdx.x;
  const int bid = blockIdx.x;

  // stage conv weights (4096 floats) as float4
  {
    const float4* s4 = (const float4*)convw;
    float4* d4 = (float4*)sh.s1.convw;
#pragma unroll
    for (int i = 0; i < 4; ++i) d4[i * 256 + tid] = s4[i * 256 + tid];
  }
  sh.s1.A[tid] = AD[tid];
  sh.s1.D[tid] = AD[NCH + tid];
  // stage 64 boards (2688 floats) as float4, scatter into padded LDS
  {
    const float4* src = (const float4*)(x + (size_t)bid * (TB * 42));
    for (int i = tid; i < (TB * 42) / 4; i += 256) {
      float4 v = src[i];
      float vals[4] = {v.x, v.y, v.z, v.w};
#pragma unroll
      for (int e = 0; e < 4; ++e) {
        int idx = i * 4 + e;
        int b = idx / 42;
        int pos = idx - b * 42;
        sh.s1.boards[b * 43 + pos] = vals[e];
      }
    }
  }
  __syncthreads();

  float acc[4][8];
#pragma unroll
  for (int i = 0; i < 4; ++i)
#pragma unroll
    for (int j = 0; j < 8; ++j) acc[i][j] = 0.f;

  const int ty = tid >> 4, tx = tid & 15;
  const int row0 = ty * 4;   // boards
  const int col0 = tx * 8;   // neurons

  for (int c = 0; c < NCH; ++c) {
    // phase 1: h-tile for this channel: conv + BN-affine + relu  -> htile[p][b]
    const float Ac = sh.s1.A[c];
    const float Dc = sh.s1.D[c];
    const float* wc = &sh.s1.convw[c * 16];
#pragma unroll
    for (int i = 0; i < 3; ++i) {
      int v = i * 256 + tid;        // 0..767
      int p = v >> 6;               // position 0..11 (wave-uniform)
      int b = v & 63;               // board = lane -> stride-43 conflict-free
      int pi = p >> 2, pj = p & 3;
      const float* bd = &sh.s1.boards[b * 43 + pi * 7 + pj];
      float s = 0.f;
#pragma unroll
      for (int di = 0; di < 4; ++di)
#pragma unroll
        for (int dj = 0; dj < 4; ++dj)
          s = fmaf(bd[di * 7 + dj], wc[di * 4 + dj], s);
      sh.s1.htile[p * 64 + b] = fmaxf(fmaf(s, Ac, Dc), 0.f);
    }
    // phase 2: stream weight slice (12 x 128) from L2, float4-coalesced
#pragma unroll
    for (int i = 0; i < 2; ++i) {
      int f4 = i * 256 + tid;
      if (f4 < 384) {
        int k = f4 >> 5;            // 32 float4 per 128-col row
        int n0 = (f4 & 31) * 4;
        int row = c * 12 + k;
        float4 v = (n0 < 64) ? *(const float4*)&pw1[row * 64 + n0]
                             : *(const float4*)&vw1[row * 64 + n0 - 64];
        *(float4*)&sh.s1.wslice[k * 128 + n0] = v;
      }
    }
    __syncthreads();
    // phase 3: (64x12)@(12x128) accumulate
#pragma unroll
    for (int k = 0; k < 12; ++k) {
      float4 hv = *(const float4*)&sh.s1.htile[k * 64 + row0];
      float4 w0 = *(const float4*)&sh.s1.wslice[k * 128 + col0];
      float4 w1 = *(const float4*)&sh.s1.wslice[k * 128 + col0 + 4];
      float h[4] = {hv.x, hv.y, hv.z, hv.w};
      float wv[8] = {w0.x, w0.y, w0.z, w0.w, w1.x, w1.y, w1.z, w1.w};
#pragma unroll
      for (int i = 0; i < 4; ++i)
#pragma unroll
        for (int j = 0; j < 8; ++j)
          acc[i][j] = fmaf(h[i], wv[j], acc[i][j]);
    }
    __syncthreads();
  }

  // ---- tail: bias+relu, write activations (64 x 128) to LDS ----
  float bias[8];
#pragma unroll
  for (int j = 0; j < 8; ++j) {
    int n = col0 + j;
    bias[j] = (n < 64) ? pb1[n] : vb1[n - 64];
  }
#pragma unroll
  for (int i = 0; i < 4; ++i) {
    float4 a0, a1;
    a0.x = fmaxf(acc[i][0] + bias[0], 0.f);
    a0.y = fmaxf(acc[i][1] + bias[1], 0.f);
    a0.z = fmaxf(acc[i][2] + bias[2], 0.f);
    a0.w = fmaxf(acc[i][3] + bias[3], 0.f);
    a1.x = fmaxf(acc[i][4] + bias[4], 0.f);
    a1.y = fmaxf(acc[i][5] + bias[5], 0.f);
    a1.z = fmaxf(acc[i][6] + bias[6], 0.f);
    a1.w = fmaxf(acc[i][7] + bias[7], 0.f);
    *(float4*)&sh.s2.act[(row0 + i) * 132 + col0] = a0;
    *(float4*)&sh.s2.act[(row0 + i) * 132 + col0 + 4] = a1;
  }
  __syncthreads();

  // ---- layer 2: 64 -> 32 both heads; 4 threads per board, 8 neurons each ----
  {
    const int b = tid >> 2, q = tid & 3;
    float accp[8], accv[8];
#pragma unroll
    for (int n = 0; n < 8; ++n) {
      accp[n] = pb2[q * 8 + n];
      accv[n] = vb2[q * 8 + n];
    }
    const float* actp = &sh.s2.act[b * 132];
    for (int m = 0; m < 64; ++m) {
      float hp = actp[m];
      float hv = actp[64 + m];
      float4 wp0 = *(const float4*)&pw2[m * 32 + q * 8];
      float4 wp1 = *(const float4*)&pw2[m * 32 + q * 8 + 4];
      float4 wv0 = *(const float4*)&vw2[m * 32 + q * 8];
      float4 wv1 = *(const float4*)&vw2[m * 32 + q * 8 + 4];
      accp[0] = fmaf(hp, wp0.x, accp[0]); accp[1] = fmaf(hp, wp0.y, accp[1]);
      accp[2] = fmaf(hp, wp0.z, accp[2]); accp[3] = fmaf(hp, wp0.w, accp[3]);
      accp[4] = fmaf(hp, wp1.x, accp[4]); accp[5] = fmaf(hp, wp1.y, accp[5]);
      accp[6] = fmaf(hp, wp1.z, accp[6]); accp[7] = fmaf(hp, wp1.w, accp[7]);
      accv[0] = fmaf(hv, wv0.x, accv[0]); accv[1] = fmaf(hv, wv0.y, accv[1]);
      accv[2] = fmaf(hv, wv0.z, accv[2]); accv[3] = fmaf(hv, wv0.w, accv[3]);
      accv[4] = fmaf(hv, wv1.x, accv[4]); accv[5] = fmaf(hv, wv1.y, accv[5]);
      accv[6] = fmaf(hv, wv1.z, accv[6]); accv[7] = fmaf(hv, wv1.w, accv[7]);
    }
    float* dst = &sh.s2.p2v2[b * 65];
#pragma unroll
    for (int n = 0; n < 8; ++n) {
      dst[q * 8 + n] = fmaxf(accp[n], 0.f);
      dst[32 + q * 8 + n] = fmaxf(accv[n], 0.f);
    }
  }
  __syncthreads();

  // ---- layer 3 + softmax / tanh: one thread per board ----
  if (tid < TB) {
    const float* pv = &sh.s2.p2v2[tid * 65];
    float lg[7];
#pragma unroll
    for (int j = 0; j < 7; ++j) lg[j] = pb3[j];
    for (int n = 0; n < 32; ++n) {
      float t = pv[n];
#pragma unroll
      for (int j = 0; j < 7; ++j) lg[j] = fmaf(t, pw3[n * 7 + j], lg[j]);
    }
    float mx = lg[0];
#pragma unroll
    for (int j = 1; j < 7; ++j) mx = fmaxf(mx, lg[j]);
    float ex[7], ssum = 0.f;
#pragma unroll
    for (int j = 0; j < 7; ++j) {
      ex[j] = expf(lg[j] - mx);
      ssum += ex[j];
    }
    float inv = 1.f / ssum;
    int bg = bid * TB + tid;
#pragma unroll
    for (int j = 0; j < 7; ++j) out[bg * 7 + j] = ex[j] * inv;
    float va = vb3[0];
#pragma unroll
    for (int n = 0; n < 32; ++n) va = fmaf(pv[32 + n], vw3[n], va);
    out[B_TOTAL * 7 + bg] = tanhf(va);
  }
}

// ---------------------------------------------------------------------------
extern "C" void kernel_launch(void* const* d_in, const int* in_sizes, int n_in,
                              void* d_out, int out_size, void* d_ws, size_t ws_size,
                              hipStream_t stream) {
  const float* x     = (const float*)d_in[0];
  const float* convw = (const float*)d_in[1];
  const float* convb = (const float*)d_in[2];
  const float* gamma = (const float*)d_in[3];
  const float* beta  = (const float*)d_in[4];
  const float* pw1 = (const float*)d_in[5];
  const float* pb1 = (const float*)d_in[6];
  const float* pw2 = (const float*)d_in[7];
  const float* pb2 = (const float*)d_in[8];
  const float* pw3 = (const float*)d_in[9];
  const float* pb3 = (const float*)d_in[10];
  const float* vw1 = (const float*)d_in[11];
  const float* vb1 = (const float*)d_in[12];
  const float* vw2 = (const float*)d_in[13];
  const float* vb2 = (const float*)d_in[14];
  const float* vw3 = (const float*)d_in[15];
  const float* vb3 = (const float*)d_in[16];
  float* out = (float*)d_out;

  float* ws   = (float*)d_ws;
  float* sums = ws;          // 42 + 1764 = 1806 floats
  float* AD   = ws + 1806;   // 512 floats

  hipMemsetAsync(sums, 0, 1806 * sizeof(float), stream);
  stats1_kernel<<<256, 256, 0, stream>>>(x, sums);
  stats2_kernel<<<1, 256, 0, stream>>>(sums, convw, convb, gamma, beta, AD);
  fused_kernel<<<512, 256, 0, stream>>>(x, convw, AD, pw1, pb1, pw2, pb2, pw3,
                                        pb3, vw1, vb1, vw2, vb2, vw3, vb3, out);
}

// Round 2
// 477.327 us; speedup vs baseline: 3.2500x; 3.2500x over previous
//
#include <hip/hip_runtime.h>
#include <math.h>

#define B_TOTAL 32768
#define TB 64
#define NCH 256
#define EPS 1e-5f

typedef unsigned short u16;
typedef __attribute__((ext_vector_type(8))) short short8;
typedef __attribute__((ext_vector_type(4))) float f32x4;

__device__ __forceinline__ u16 f2bf(float f) {
  unsigned int u = __builtin_bit_cast(unsigned int, f);
  u = (u + 0x7fffu + ((u >> 16) & 1u)) >> 16;
  return (u16)u;
}

// ---------------------------------------------------------------------------
// stats pass 1: per-block partial sums (no atomics).
// partial[bid][0..41] = sum_b x[b,i]; partial[bid][42..1805] = sum x_i x_j
// ---------------------------------------------------------------------------
__global__ __launch_bounds__(256) void stats1_kernel(const float* __restrict__ x,
                                                     float* __restrict__ partial) {
  __shared__ float xb[128 * 42];
  const int tid = threadIdx.x;
  const int bid = blockIdx.x;
  const float4* src = (const float4*)(x + (size_t)bid * 128 * 42);
  float4* dst = (float4*)xb;
  for (int i = tid; i < 1344; i += 256) dst[i] = src[i];
  __syncthreads();
  float* outp = partial + (size_t)bid * 1806;
  for (int s = 0; s < 7; ++s) {
    int pidx = s * 256 + tid;
    if (pidx < 42 * 42) {
      int i = pidx / 42;
      int j = pidx - i * 42;
      float acc = 0.f;
      for (int b = 0; b < 128; ++b)
        acc = fmaf(xb[b * 42 + i], xb[b * 42 + j], acc);
      outp[42 + pidx] = acc;
    }
  }
  if (tid < 42) {
    float acc = 0.f;
    for (int b = 0; b < 128; ++b) acc += xb[b * 42 + tid];
    outp[tid] = acc;
  }
}

// reduce 256 partials -> sums[1806]
__global__ __launch_bounds__(256) void reduce_kernel(const float* __restrict__ partial,
                                                     float* __restrict__ sums) {
  int idx = blockIdx.x * 256 + threadIdx.x;
  if (idx >= 1806) return;
  float a = 0.f;
  for (int b = 0; b < 256; ++b) a += partial[(size_t)b * 1806 + idx];
  sums[idx] = a;
}

// ---------------------------------------------------------------------------
// stats pass 2: per-channel BN-affine coefficients (A, D).
// ---------------------------------------------------------------------------
__global__ __launch_bounds__(256) void stats2_kernel(
    const float* __restrict__ sums, const float* __restrict__ convw,
    const float* __restrict__ convb, const float* __restrict__ gamma,
    const float* __restrict__ beta, float* __restrict__ AD) {
  __shared__ float sM[42];
  __shared__ float sS[42 * 42];
  const int tid = threadIdx.x;
  const float invB = 1.f / (float)B_TOTAL;
  for (int i = tid; i < 42 + 42 * 42; i += 256) {
    float v = sums[i] * invB;
    if (i < 42) sM[i] = v; else sS[i - 42] = v;
  }
  __syncthreads();
  float w[16];
#pragma unroll
  for (int k = 0; k < 16; ++k) w[k] = convw[tid * 16 + k];
  const float cb = convb[tid];
  float accm = 0.f, acc2 = 0.f;
  for (int p = 0; p < 12; ++p) {
    const int pi = p >> 2, pj = p & 3;
    int idx[16];
#pragma unroll
    for (int k = 0; k < 16; ++k) idx[k] = (pi + (k >> 2)) * 7 + pj + (k & 3);
    float dm = 0.f, q = 0.f;
#pragma unroll
    for (int k = 0; k < 16; ++k) {
      dm = fmaf(w[k], sM[idx[k]], dm);
      float t = 0.f;
      const float* Srow = &sS[idx[k] * 42];
#pragma unroll
      for (int k2 = 0; k2 < 16; ++k2) t = fmaf(w[k2], Srow[idx[k2]], t);
      q = fmaf(w[k], t, q);
    }
    accm += dm;
    acc2 += cb * cb + 2.f * cb * dm + q;
  }
  const float meanY = cb + accm * (1.f / 12.f);
  const float EY2 = acc2 * (1.f / 12.f);
  float var = EY2 - meanY * meanY;
  var = fmaxf(var, 0.f);
  const float alpha = gamma[tid] * rsqrtf(var + EPS);
  AD[tid] = alpha;
  AD[NCH + tid] = beta[tid] + alpha * (cb - meanY);
}

// ---------------------------------------------------------------------------
// pack [pw1|vw1] (3072x128 fp32) into bf16 B-fragment order.
// k remap: k = g*96 + p*8 + cl  (group g of 8 channels, position p, ch cl).
// chunk idx = (K*128 + c)*4 + q holds 8 bf16: W[r][c], r = (K/3*8+j)*12 + (K%3)*4 + q
// ---------------------------------------------------------------------------
__global__ __launch_bounds__(256) void pack_kernel(const float* __restrict__ pw1,
                                                   const float* __restrict__ vw1,
                                                   u16* __restrict__ Wp) {
  int idx = blockIdx.x * 256 + threadIdx.x;  // < 49152
  int q = idx & 3, c = (idx >> 2) & 127, K = idx >> 9;
  int g = K / 3, kt = K - g * 3;
  union { u16 s[8]; uint4 v; } pk;
#pragma unroll
  for (int j = 0; j < 8; ++j) {
    int r = (g * 8 + j) * 12 + kt * 4 + q;
    float w = (c < 64) ? pw1[r * 64 + c] : vw1[r * 64 + (c - 64)];
    pk.s[j] = f2bf(w);
  }
  *(uint4*)&Wp[(size_t)idx * 8] = pk.v;
}

// ---------------------------------------------------------------------------
// fused: conv + BN-affine + relu -> bf16 A-fragments -> MFMA GEMM (64x128 per
// block over K=3072) -> heads.
// ---------------------------------------------------------------------------
struct S1 {
  float boards[TB * 43];     // 11008 B, stride 43 -> conflict-free lane=board
  u16 Apack[12 * 64 * 8];    // [k-octet o=p][board][j]  12288 B
  u16 Bpack[1536 * 8];       // group slice of Wp        24576 B
};
struct S2 {
  float act[TB * 132];
  float p2v2[TB * 65];
};
union Sh { S1 s1; S2 s2; };

__global__ __launch_bounds__(256, 2) void fused_kernel(
    const float* __restrict__ x, const float* __restrict__ convw,
    const float* __restrict__ AD, const u16* __restrict__ Wp,
    const float* __restrict__ pb1, const float* __restrict__ vb1,
    const float* __restrict__ pw2, const float* __restrict__ pb2,
    const float* __restrict__ pw3, const float* __restrict__ pb3,
    const float* __restrict__ vw2, const float* __restrict__ vb2,
    const float* __restrict__ vw3, const float* __restrict__ vb3,
    float* __restrict__ out) {
  __shared__ Sh sh;
  const int tid = threadIdx.x;
  const int bid = blockIdx.x;
  const int l = tid & 63, wv = tid >> 6;
  const int lm = l & 15, lq = l >> 4;

  // stage 64 boards into padded LDS
  {
    const float4* src = (const float4*)(x + (size_t)bid * (TB * 42));
    for (int i = tid; i < (TB * 42) / 4; i += 256) {
      float4 v = src[i];
      float vals[4] = {v.x, v.y, v.z, v.w};
#pragma unroll
      for (int e = 0; e < 4; ++e) {
        int idx = i * 4 + e;
        int b = idx / 42;
        int pos = idx - b * 42;
        sh.s1.boards[b * 43 + pos] = vals[e];
      }
    }
  }
  __syncthreads();

  f32x4 acc[4][2];
#pragma unroll
  for (int R = 0; R < 4; ++R)
#pragma unroll
    for (int t = 0; t < 2; ++t)
#pragma unroll
      for (int r = 0; r < 4; ++r) acc[R][t][r] = 0.f;

  for (int g = 0; g < 32; ++g) {
    // prefetch B slice (24576 B) into regs
    uint4 breg[6];
    const u16* Wg = Wp + (size_t)g * 12288;
#pragma unroll
    for (int ii = 0; ii < 6; ++ii)
      breg[ii] = *(const uint4*)&Wg[(size_t)(ii * 256 + tid) * 8];

    // phase A: h for 8 channels x 12 positions x 64 boards, bf16 A-frag order
#pragma unroll
    for (int i = 0; i < 3; ++i) {
      const int p = i * 4 + wv;       // wave-uniform position 0..11
      const int pi = p >> 2, pj = p & 3;
      const float* bd = &sh.s1.boards[l * 43 + pi * 7 + pj];
      float bv[16];
#pragma unroll
      for (int di = 0; di < 4; ++di)
#pragma unroll
        for (int dj = 0; dj < 4; ++dj) bv[di * 4 + dj] = bd[di * 7 + dj];
      union { u16 s[8]; uint4 v; } pk;
#pragma unroll
      for (int j = 0; j < 8; ++j) {
        const int ch = g * 8 + j;     // wave-uniform -> s_load weights
        const float* wc = convw + ch * 16;
        float s = 0.f;
#pragma unroll
        for (int t = 0; t < 16; ++t) s = fmaf(bv[t], wc[t], s);
        float h = fmaxf(fmaf(s, AD[ch], AD[NCH + ch]), 0.f);
        pk.s[j] = f2bf(h);
      }
      *(uint4*)&sh.s1.Apack[(size_t)(p * 64 + l) * 8] = pk.v;
    }
    // B regs -> LDS
#pragma unroll
    for (int ii = 0; ii < 6; ++ii)
      *(uint4*)&sh.s1.Bpack[(size_t)(ii * 256 + tid) * 8] = breg[ii];
    __syncthreads();

    // MFMA: 3 k-tiles x (4 row-tiles x 2 col-tiles per wave)
#pragma unroll
    for (int K = 0; K < 3; ++K) {
      short8 bf0 = *(const short8*)&sh.s1.Bpack[(size_t)(((K * 128 + (wv * 2 + 0) * 16 + lm) * 4 + lq)) * 8];
      short8 bf1 = *(const short8*)&sh.s1.Bpack[(size_t)(((K * 128 + (wv * 2 + 1) * 16 + lm) * 4 + lq)) * 8];
#pragma unroll
      for (int R = 0; R < 4; ++R) {
        short8 af = *(const short8*)&sh.s1.Apack[(size_t)(((K * 4 + lq) * 64 + R * 16 + lm)) * 8];
        acc[R][0] = __builtin_amdgcn_mfma_f32_16x16x32_bf16(af, bf0, acc[R][0], 0, 0, 0);
        acc[R][1] = __builtin_amdgcn_mfma_f32_16x16x32_bf16(af, bf1, acc[R][1], 0, 0, 0);
      }
    }
    __syncthreads();
  }

  // epilogue: bias + relu -> act LDS (cols 0..63 policy, 64..127 value)
  {
    const int n0 = wv * 32 + lm;
    const int n1 = n0 + 16;
    const float b0 = (n0 < 64) ? pb1[n0] : vb1[n0 - 64];
    const float b1 = (n1 < 64) ? pb1[n1] : vb1[n1 - 64];
#pragma unroll
    for (int R = 0; R < 4; ++R)
#pragma unroll
      for (int r = 0; r < 4; ++r) {
        int row = R * 16 + lq * 4 + r;
        sh.s2.act[row * 132 + n0] = fmaxf(acc[R][0][r] + b0, 0.f);
        sh.s2.act[row * 132 + n1] = fmaxf(acc[R][1][r] + b1, 0.f);
      }
  }
  __syncthreads();

  // layer 2: 64 -> 32 both heads; 4 threads per board, 8 neurons each
  {
    const int b = tid >> 2, q = tid & 3;
    float accp[8], accv[8];
#pragma unroll
    for (int n = 0; n < 8; ++n) {
      accp[n] = pb2[q * 8 + n];
      accv[n] = vb2[q * 8 + n];
    }
    const float* actp = &sh.s2.act[b * 132];
    for (int m = 0; m < 64; ++m) {
      float hp = actp[m];
      float hv = actp[64 + m];
      float4 wp0 = *(const float4*)&pw2[m * 32 + q * 8];
      float4 wp1 = *(const float4*)&pw2[m * 32 + q * 8 + 4];
      float4 wv0 = *(const float4*)&vw2[m * 32 + q * 8];
      float4 wv1 = *(const float4*)&vw2[m * 32 + q * 8 + 4];
      accp[0] = fmaf(hp, wp0.x, accp[0]); accp[1] = fmaf(hp, wp0.y, accp[1]);
      accp[2] = fmaf(hp, wp0.z, accp[2]); accp[3] = fmaf(hp, wp0.w, accp[3]);
      accp[4] = fmaf(hp, wp1.x, accp[4]); accp[5] = fmaf(hp, wp1.y, accp[5]);
      accp[6] = fmaf(hp, wp1.z, accp[6]); accp[7] = fmaf(hp, wp1.w, accp[7]);
      accv[0] = fmaf(hv, wv0.x, accv[0]); accv[1] = fmaf(hv, wv0.y, accv[1]);
      accv[2] = fmaf(hv, wv0.z, accv[2]); accv[3] = fmaf(hv, wv0.w, accv[3]);
      accv[4] = fmaf(hv, wv1.x, accv[4]); accv[5] = fmaf(hv, wv1.y, accv[5]);
      accv[6] = fmaf(hv, wv1.z, accv[6]); accv[7] = fmaf(hv, wv1.w, accv[7]);
    }
    float* dst = &sh.s2.p2v2[b * 65];
#pragma unroll
    for (int n = 0; n < 8; ++n) {
      dst[q * 8 + n] = fmaxf(accp[n], 0.f);
      dst[32 + q * 8 + n] = fmaxf(accv[n], 0.f);
    }
  }
  __syncthreads();

  // layer 3 + softmax / tanh: one thread per board
  if (tid < TB) {
    const float* pv = &sh.s2.p2v2[tid * 65];
    float lg[7];
#pragma unroll
    for (int j = 0; j < 7; ++j) lg[j] = pb3[j];
    for (int n = 0; n < 32; ++n) {
      float t = pv[n];
#pragma unroll
      for (int j = 0; j < 7; ++j) lg[j] = fmaf(t, pw3[n * 7 + j], lg[j]);
    }
    float mx = lg[0];
#pragma unroll
    for (int j = 1; j < 7; ++j) mx = fmaxf(mx, lg[j]);
    float ex[7], ssum = 0.f;
#pragma unroll
    for (int j = 0; j < 7; ++j) {
      ex[j] = expf(lg[j] - mx);
      ssum += ex[j];
    }
    float inv = 1.f / ssum;
    int bg = bid * TB + tid;
#pragma unroll
    for (int j = 0; j < 7; ++j) out[bg * 7 + j] = ex[j] * inv;
    float va = vb3[0];
#pragma unroll
    for (int n = 0; n < 32; ++n) va = fmaf(pv[32 + n], vw3[n], va);
    out[B_TOTAL * 7 + bg] = tanhf(va);
  }
}

// ---------------------------------------------------------------------------
extern "C" void kernel_launch(void* const* d_in, const int* in_sizes, int n_in,
                              void* d_out, int out_size, void* d_ws, size_t ws_size,
                              hipStream_t stream) {
  const float* x     = (const float*)d_in[0];
  const float* convw = (const float*)d_in[1];
  const float* convb = (const float*)d_in[2];
  const float* gamma = (const float*)d_in[3];
  const float* beta  = (const float*)d_in[4];
  const float* pw1 = (const float*)d_in[5];
  const float* pb1 = (const float*)d_in[6];
  const float* pw2 = (const float*)d_in[7];
  const float* pb2 = (const float*)d_in[8];
  const float* pw3 = (const float*)d_in[9];
  const float* pb3 = (const float*)d_in[10];
  const float* vw1 = (const float*)d_in[11];
  const float* vb1 = (const float*)d_in[12];
  const float* vw2 = (const float*)d_in[13];
  const float* vb2 = (const float*)d_in[14];
  const float* vw3 = (const float*)d_in[15];
  const float* vb3 = (const float*)d_in[16];
  float* out = (float*)d_out;

  float* ws      = (float*)d_ws;
  float* partial = ws;                       // 256*1806 = 462336 floats
  float* sums    = ws + 462336;              // 1806 floats
  float* AD      = ws + 464160;              // 512 floats
  u16*   Wpack   = (u16*)(ws + 464672);      // 393216 bf16 (768 KB)

  stats1_kernel<<<256, 256, 0, stream>>>(x, partial);
  reduce_kernel<<<8, 256, 0, stream>>>(partial, sums);
  stats2_kernel<<<1, 256, 0, stream>>>(sums, convw, convb, gamma, beta, AD);
  pack_kernel<<<192, 256, 0, stream>>>(pw1, vw1, Wpack);
  fused_kernel<<<512, 256, 0, stream>>>(x, convw, AD, Wpack, pb1, vb1,
                                        pw2, pb2, pw3, pb3, vw2, vb2, vw3, vb3,
                                        out);
}

// Round 3
// 313.617 us; speedup vs baseline: 4.9465x; 1.5220x over previous
//
#include <hip/hip_runtime.h>
#include <math.h>

#define B_TOTAL 32768
#define TB 64
#define NCH 256
#define EPS 1e-5f

typedef unsigned short u16;
typedef __attribute__((ext_vector_type(8))) short short8;
typedef __attribute__((ext_vector_type(4))) float f32x4;

__device__ __forceinline__ u16 f2bf(float f) {
  unsigned int u = __builtin_bit_cast(unsigned int, f);
  u = (u + 0x7fffu + ((u >> 16) & 1u)) >> 16;
  return (u16)u;
}

__device__ __forceinline__ void gl_lds16(const void* g, void* l) {
  __builtin_amdgcn_global_load_lds(
      (const __attribute__((address_space(1))) unsigned int*)g,
      (__attribute__((address_space(3))) unsigned int*)l, 16, 0, 0);
}

// ---------------------------------------------------------------------------
// stats1: 4x4 register-tiled second moments + means, fp32 atomics to sums.
// sums[0..41] = sum_b x[b,i]; sums[42..1805] = sum_b x_i x_j (42x42)
// ---------------------------------------------------------------------------
__global__ __launch_bounds__(256) void stats1_kernel(const float* __restrict__ x,
                                                     float* __restrict__ sums) {
  __shared__ float xb[128 * 44];
  const int tid = threadIdx.x;
  const int bid = blockIdx.x;
  if (tid < 128) { xb[tid * 44 + 42] = 0.f; xb[tid * 44 + 43] = 0.f; }
  const float4* src = (const float4*)(x + (size_t)bid * 128 * 42);
  for (int i = tid; i < 1344; i += 256) {
    float4 v = src[i];
    float vals[4] = {v.x, v.y, v.z, v.w};
#pragma unroll
    for (int e = 0; e < 4; ++e) {
      int idx = i * 4 + e;
      int b = idx / 42;
      int pos = idx - b * 42;
      xb[b * 44 + pos] = vals[e];
    }
  }
  __syncthreads();
  if (tid < 121) {
    const int ti = tid / 11, tj = tid - (tid / 11) * 11;
    const int i0 = ti * 4, j0 = tj * 4;
    float acc[4][4];
#pragma unroll
    for (int i = 0; i < 4; ++i)
#pragma unroll
      for (int j = 0; j < 4; ++j) acc[i][j] = 0.f;
    for (int b = 0; b < 128; ++b) {
      f32x4 va = *(const f32x4*)&xb[b * 44 + i0];
      f32x4 vb = *(const f32x4*)&xb[b * 44 + j0];
#pragma unroll
      for (int i = 0; i < 4; ++i)
#pragma unroll
        for (int j = 0; j < 4; ++j) acc[i][j] = fmaf(va[i], vb[j], acc[i][j]);
    }
#pragma unroll
    for (int i = 0; i < 4; ++i)
#pragma unroll
      for (int j = 0; j < 4; ++j) {
        int gi = i0 + i, gj = j0 + j;
        if (gi < 42 && gj < 42) atomicAdd(&sums[42 + gi * 42 + gj], acc[i][j]);
      }
  } else if (tid >= 128 && tid < 170) {
    const int c = tid - 128;
    float a = 0.f;
    for (int b = 0; b < 128; ++b) a += xb[b * 44 + c];
    atomicAdd(&sums[c], a);
  }
}

// ---------------------------------------------------------------------------
// stats2: per-channel BN-affine coefficients A (scale) and D (shift).
// ---------------------------------------------------------------------------
__global__ __launch_bounds__(256) void stats2_kernel(
    const float* __restrict__ sums, const float* __restrict__ convw,
    const float* __restrict__ convb, const float* __restrict__ gamma,
    const float* __restrict__ beta, float* __restrict__ AD) {
  __shared__ float sM[42];
  __shared__ float sS[42 * 42];
  const int tid = threadIdx.x;
  const float invB = 1.f / (float)B_TOTAL;
  for (int i = tid; i < 42 + 42 * 42; i += 256) {
    float v = sums[i] * invB;
    if (i < 42) sM[i] = v; else sS[i - 42] = v;
  }
  __syncthreads();
  float w[16];
#pragma unroll
  for (int k = 0; k < 16; ++k) w[k] = convw[tid * 16 + k];
  const float cb = convb[tid];
  float accm = 0.f, acc2 = 0.f;
  for (int p = 0; p < 12; ++p) {
    const int pi = p >> 2, pj = p & 3;
    int idx[16];
#pragma unroll
    for (int k = 0; k < 16; ++k) idx[k] = (pi + (k >> 2)) * 7 + pj + (k & 3);
    float dm = 0.f, q = 0.f;
#pragma unroll
    for (int k = 0; k < 16; ++k) {
      dm = fmaf(w[k], sM[idx[k]], dm);
      float t = 0.f;
      const float* Srow = &sS[idx[k] * 42];
#pragma unroll
      for (int k2 = 0; k2 < 16; ++k2) t = fmaf(w[k2], Srow[idx[k2]], t);
      q = fmaf(w[k], t, q);
    }
    accm += dm;
    acc2 += cb * cb + 2.f * cb * dm + q;
  }
  const float meanY = cb + accm * (1.f / 12.f);
  const float EY2 = acc2 * (1.f / 12.f);
  float var = EY2 - meanY * meanY;
  var = fmaxf(var, 0.f);
  const float alpha = gamma[tid] * rsqrtf(var + EPS);
  AD[tid] = alpha;
  AD[NCH + tid] = beta[tid] + alpha * (cb - meanY);
}

// ---------------------------------------------------------------------------
// pack [pw1|vw1] -> bf16, fragment-major so fused staging is a linear copy:
// chunk (8 bf16) linear id = g*1536 + kt*512 + ctl*64 + lq*16 + lm
// holds W[r][col], r = (g*8+j)*12 + (kt*4+lq), col = ctl*16+lm, j=0..7
// ---------------------------------------------------------------------------
__global__ __launch_bounds__(256) void pack_kernel(const float* __restrict__ pw1,
                                                   const float* __restrict__ vw1,
                                                   u16* __restrict__ Wp) {
  const int id = blockIdx.x * 256 + threadIdx.x;  // < 49152
  const int g = id / 1536;
  const int rem = id - g * 1536;
  const int kt = rem >> 9;
  const int ctl = (rem >> 6) & 7;
  const int lq = (rem >> 4) & 3;
  const int lm = rem & 15;
  const int p = kt * 4 + lq;
  const int col = ctl * 16 + lm;
  union { u16 s[8]; uint4 v; } pk;
#pragma unroll
  for (int j = 0; j < 8; ++j) {
    int r = (g * 8 + j) * 12 + p;
    float w = (col < 64) ? pw1[r * 64 + col] : vw1[r * 64 + (col - 64)];
    pk.s[j] = f2bf(w);
  }
  *(uint4*)&Wp[(size_t)id * 8] = pk.v;
}

// ---------------------------------------------------------------------------
// fused: MFMA conv (16x16x32, half-K zero) + BN affine + relu -> Apack
//        -> MFMA GEMM (64x128, K=3072) -> heads.
// ---------------------------------------------------------------------------
struct S1 {
  u16 Bpatch[1536 * 8];                 // 24576 B [nt][lq2][lm][8]
  u16 zpad[8];                          // 16 B of zeros
  float ADs[512];                       // 2048 B
  u16 Apack[2 * 12 * 64 * 8];           // 24576 B [par][p][board][8]
  union { u16 Bslice[1536 * 8]; float boards[TB * 43]; } u;  // 24576 B
};
struct S2 {
  float act[TB * 132];
  float p2v2[TB * 65];
};
union Sh { S1 s1; S2 s2; };

__global__ __launch_bounds__(256, 2) void fused_kernel(
    const float* __restrict__ x, const float* __restrict__ convw,
    const float* __restrict__ AD, const u16* __restrict__ Wp,
    const float* __restrict__ pb1, const float* __restrict__ vb1,
    const float* __restrict__ pw2, const float* __restrict__ pb2,
    const float* __restrict__ pw3, const float* __restrict__ pb3,
    const float* __restrict__ vw2, const float* __restrict__ vb2,
    const float* __restrict__ vw3, const float* __restrict__ vb3,
    float* __restrict__ out) {
  __shared__ Sh sh;
  const int tid = threadIdx.x;
  const int bid = blockIdx.x;
  const int l = tid & 63, wv = tid >> 6;
  const int lm = l & 15, lq = l >> 4;

  // stage boards into padded LDS (overlaps Bslice region; used pre-loop only)
  {
    const float4* src = (const float4*)(x + (size_t)bid * (TB * 42));
    for (int i = tid; i < (TB * 42) / 4; i += 256) {
      float4 v = src[i];
      float vals[4] = {v.x, v.y, v.z, v.w};
#pragma unroll
      for (int e = 0; e < 4; ++e) {
        int idx = i * 4 + e;
        int b = idx / 42;
        int pos = idx - b * 42;
        sh.s1.u.boards[b * 43 + pos] = vals[e];
      }
    }
  }
  sh.s1.ADs[tid] = AD[tid];
  sh.s1.ADs[256 + tid] = AD[256 + tid];
  if (tid < 8) sh.s1.zpad[tid] = 0;
  __syncthreads();

  // build conv patch B-fragments (bf16): slot s -> (nt, lq2, lm), 8 k-values
#pragma unroll
  for (int i = 0; i < 6; ++i) {
    int s = i * 256 + tid;
    int plm = s & 15, lq2 = (s >> 4) & 1, nt = s >> 5;
    int p = nt >> 2, b = ((nt & 3) << 4) | plm;
    int pi = p >> 2, pj = p & 3;
    const float* bd = &sh.s1.u.boards[b * 43 + (pi + lq2 * 2) * 7 + pj];
    union { u16 s8[8]; uint4 q; } pk;
#pragma unroll
    for (int d = 0; d < 4; ++d) {
      pk.s8[d] = f2bf(bd[d]);
      pk.s8[4 + d] = f2bf(bd[7 + d]);
    }
    *(uint4*)&sh.s1.Bpatch[(size_t)((nt * 2 + lq2) * 16 + plm) * 8] = pk.q;
  }
  __syncthreads();

  f32x4 acc[4][2];
#pragma unroll
  for (int R = 0; R < 4; ++R)
#pragma unroll
    for (int t = 0; t < 2; ++t)
#pragma unroll
      for (int r = 0; r < 4; ++r) acc[R][t][r] = 0.f;

  for (int gg = 0; gg < 16; ++gg) {
    const int g0 = gg * 2;
    // async-stage Bslice(g0) (prev barrier guarantees region free)
    {
      const u16* gsrc = Wp + (size_t)g0 * 12288;
#pragma unroll
      for (int i = 0; i < 6; ++i)
        gl_lds16(gsrc + (size_t)(i * 256 + tid) * 8,
                 &sh.s1.u.Bslice[(size_t)(i * 256 + tid) * 8]);
    }
    // conv via MFMA for 16 channels (groups g0, g0+1), K=16 in a K=32 op
    {
      const int ch = gg * 16 + lm;
      union { u16 s8[8]; short8 v; } aw;
      if (lq < 2) {
        const float* wsrc = convw + ch * 16 + lq * 8;
#pragma unroll
        for (int t = 0; t < 8; ++t) aw.s8[t] = f2bf(wsrc[t]);
      } else {
#pragma unroll
        for (int t = 0; t < 8; ++t) aw.s8[t] = 0;
      }
      const f32x4 A4 = *(const f32x4*)&sh.s1.ADs[gg * 16 + lq * 4];
      const f32x4 D4 = *(const f32x4*)&sh.s1.ADs[256 + gg * 16 + lq * 4];
      const int par = lq >> 1;
      const int joff = (lq & 1) * 4;
#pragma unroll
      for (int i = 0; i < 12; ++i) {
        const int nt = i * 4 + wv;
        const u16* bs = (lq < 2)
            ? &sh.s1.Bpatch[(size_t)((nt * 2 + lq) * 16 + lm) * 8]
            : sh.s1.zpad;
        short8 bf = *(const short8*)bs;
        f32x4 c = {0.f, 0.f, 0.f, 0.f};
        c = __builtin_amdgcn_mfma_f32_16x16x32_bf16(aw.v, bf, c, 0, 0, 0);
        const int p = nt >> 2, b = ((nt & 3) << 4) | lm;
        union { u16 s4[4]; uint2 q; } hp;
#pragma unroll
        for (int r = 0; r < 4; ++r)
          hp.s4[r] = f2bf(fmaxf(fmaf(c[r], A4[r], D4[r]), 0.f));
        *(uint2*)&sh.s1.Apack[(size_t)(((par * 12 + p) * 64 + b) * 8) + joff] = hp.q;
      }
    }
    __syncthreads();  // Apack + Bslice(g0) ready

#pragma unroll
    for (int par = 0; par < 2; ++par) {
      // GEMM2 for group g0+par
#pragma unroll
      for (int K = 0; K < 3; ++K) {
        short8 bf0 = *(const short8*)&sh.s1.u.Bslice[
            (size_t)(K * 4096 + (wv * 2 + 0) * 512 + lq * 128 + lm * 8)];
        short8 bf1 = *(const short8*)&sh.s1.u.Bslice[
            (size_t)(K * 4096 + (wv * 2 + 1) * 512 + lq * 128 + lm * 8)];
#pragma unroll
        for (int R = 0; R < 4; ++R) {
          short8 af = *(const short8*)&sh.s1.Apack[
              (size_t)(((par * 12 + K * 4 + lq) * 64 + R * 16 + lm) * 8)];
          acc[R][0] = __builtin_amdgcn_mfma_f32_16x16x32_bf16(af, bf0, acc[R][0], 0, 0, 0);
          acc[R][1] = __builtin_amdgcn_mfma_f32_16x16x32_bf16(af, bf1, acc[R][1], 0, 0, 0);
        }
      }
      __syncthreads();  // done reading Bslice (and, on par=1, Apack)
      if (par == 0) {
        const u16* gsrc = Wp + (size_t)(g0 + 1) * 12288;
#pragma unroll
        for (int i = 0; i < 6; ++i)
          gl_lds16(gsrc + (size_t)(i * 256 + tid) * 8,
                   &sh.s1.u.Bslice[(size_t)(i * 256 + tid) * 8]);
        __syncthreads();  // wait staging of Bslice(g0+1)
      }
    }
  }

  // epilogue: bias + relu -> act LDS (cols 0..63 policy, 64..127 value)
  {
    const int n0 = wv * 32 + lm;
    const int n1 = n0 + 16;
    const float b0 = (n0 < 64) ? pb1[n0] : vb1[n0 - 64];
    const float b1 = (n1 < 64) ? pb1[n1] : vb1[n1 - 64];
#pragma unroll
    for (int R = 0; R < 4; ++R)
#pragma unroll
      for (int r = 0; r < 4; ++r) {
        int row = R * 16 + lq * 4 + r;
        sh.s2.act[row * 132 + n0] = fmaxf(acc[R][0][r] + b0, 0.f);
        sh.s2.act[row * 132 + n1] = fmaxf(acc[R][1][r] + b1, 0.f);
      }
  }
  __syncthreads();

  // layer 2: 64 -> 32 both heads; 4 threads per board, 8 neurons each
  {
    const int b = tid >> 2, q = tid & 3;
    float accp[8], accv[8];
#pragma unroll
    for (int n = 0; n < 8; ++n) {
      accp[n] = pb2[q * 8 + n];
      accv[n] = vb2[q * 8 + n];
    }
    const float* actp = &sh.s2.act[b * 132];
    for (int m = 0; m < 64; ++m) {
      float hp = actp[m];
      float hv = actp[64 + m];
      float4 wp0 = *(const float4*)&pw2[m * 32 + q * 8];
      float4 wp1 = *(const float4*)&pw2[m * 32 + q * 8 + 4];
      float4 wv0 = *(const float4*)&vw2[m * 32 + q * 8];
      float4 wv1 = *(const float4*)&vw2[m * 32 + q * 8 + 4];
      accp[0] = fmaf(hp, wp0.x, accp[0]); accp[1] = fmaf(hp, wp0.y, accp[1]);
      accp[2] = fmaf(hp, wp0.z, accp[2]); accp[3] = fmaf(hp, wp0.w, accp[3]);
      accp[4] = fmaf(hp, wp1.x, accp[4]); accp[5] = fmaf(hp, wp1.y, accp[5]);
      accp[6] = fmaf(hp, wp1.z, accp[6]); accp[7] = fmaf(hp, wp1.w, accp[7]);
      accv[0] = fmaf(hv, wv0.x, accv[0]); accv[1] = fmaf(hv, wv0.y, accv[1]);
      accv[2] = fmaf(hv, wv0.z, accv[2]); accv[3] = fmaf(hv, wv0.w, accv[3]);
      accv[4] = fmaf(hv, wv1.x, accv[4]); accv[5] = fmaf(hv, wv1.y, accv[5]);
      accv[6] = fmaf(hv, wv1.z, accv[6]); accv[7] = fmaf(hv, wv1.w, accv[7]);
    }
    float* dst = &sh.s2.p2v2[b * 65];
#pragma unroll
    for (int n = 0; n < 8; ++n) {
      dst[q * 8 + n] = fmaxf(accp[n], 0.f);
      dst[32 + q * 8 + n] = fmaxf(accv[n], 0.f);
    }
  }
  __syncthreads();

  // layer 3 + softmax / tanh: one thread per board
  if (tid < TB) {
    const float* pv = &sh.s2.p2v2[tid * 65];
    float lg[7];
#pragma unroll
    for (int j = 0; j < 7; ++j) lg[j] = pb3[j];
    for (int n = 0; n < 32; ++n) {
      float t = pv[n];
#pragma unroll
      for (int j = 0; j < 7; ++j) lg[j] = fmaf(t, pw3[n * 7 + j], lg[j]);
    }
    float mx = lg[0];
#pragma unroll
    for (int j = 1; j < 7; ++j) mx = fmaxf(mx, lg[j]);
    float ex[7], ssum = 0.f;
#pragma unroll
    for (int j = 0; j < 7; ++j) {
      ex[j] = expf(lg[j] - mx);
      ssum += ex[j];
    }
    float inv = 1.f / ssum;
    int bg = bid * TB + tid;
#pragma unroll
    for (int j = 0; j < 7; ++j) out[bg * 7 + j] = ex[j] * inv;
    float va = vb3[0];
#pragma unroll
    for (int n = 0; n < 32; ++n) va = fmaf(pv[32 + n], vw3[n], va);
    out[B_TOTAL * 7 + bg] = tanhf(va);
  }
}

// ---------------------------------------------------------------------------
extern "C" void kernel_launch(void* const* d_in, const int* in_sizes, int n_in,
                              void* d_out, int out_size, void* d_ws, size_t ws_size,
                              hipStream_t stream) {
  const float* x     = (const float*)d_in[0];
  const float* convw = (const float*)d_in[1];
  const float* convb = (const float*)d_in[2];
  const float* gamma = (const float*)d_in[3];
  const float* beta  = (const float*)d_in[4];
  const float* pw1 = (const float*)d_in[5];
  const float* pb1 = (const float*)d_in[6];
  const float* pw2 = (const float*)d_in[7];
  const float* pb2 = (const float*)d_in[8];
  const float* pw3 = (const float*)d_in[9];
  const float* pb3 = (const float*)d_in[10];
  const float* vw1 = (const float*)d_in[11];
  const float* vb1 = (const float*)d_in[12];
  const float* vw2 = (const float*)d_in[13];
  const float* vb2 = (const float*)d_in[14];
  const float* vw3 = (const float*)d_in[15];
  const float* vb3 = (const float*)d_in[16];
  float* out = (float*)d_out;

  float* ws   = (float*)d_ws;
  float* sums = ws;                       // 1806 f32 (+pad)
  float* AD   = ws + 1856;                // 512 f32
  u16*   Wp   = (u16*)(ws + 2368);        // 393216 bf16 (768 KB), 16B-aligned

  hipMemsetAsync(sums, 0, 1806 * sizeof(float), stream);
  stats1_kernel<<<256, 256, 0, stream>>>(x, sums);
  stats2_kernel<<<1, 256, 0, stream>>>(sums, convw, convb, gamma, beta, AD);
  pack_kernel<<<192, 256, 0, stream>>>(pw1, vw1, Wp);
  fused_kernel<<<512, 256, 0, stream>>>(x, convw, AD, Wp, pb1, vb1,
                                        pw2, pb2, pw3, pb3, vw2, vb2, vw3, vb3,
                                        out);
}

// Round 4
// 269.862 us; speedup vs baseline: 5.7486x; 1.1621x over previous
//
#include <hip/hip_runtime.h>
#include <math.h>

#define B_TOTAL 32768
#define TB 64
#define NCH 256
#define EPS 1e-5f

typedef unsigned short u16;
typedef __attribute__((ext_vector_type(8))) short short8;
typedef __attribute__((ext_vector_type(4))) float f32x4;

__device__ __forceinline__ u16 f2bf(float f) {
  unsigned int u = __builtin_bit_cast(unsigned int, f);
  u = (u + 0x7fffu + ((u >> 16) & 1u)) >> 16;
  return (u16)u;
}
__device__ __forceinline__ short8 u4s8(uint4 v) {
  return __builtin_bit_cast(short8, v);
}

// ---------------------------------------------------------------------------
// prep: blocks 0..63 = stats partials (512 boards each, 4 passes, no atomics);
//       blocks 64..255 = weight pack (bf16 B-fragment order).
// partial row: [0..41]=means-sums, [42+i*42+j]=second moments. stride 1856.
// Wp chunk id = g*1536 + kt*512 + ctl*64 + lq*16 + lm holds 8 bf16:
//   W[r][col], r=(g*8+j)*12 + kt*4+lq, col=ctl*16+lm, j=0..7
// ---------------------------------------------------------------------------
__global__ __launch_bounds__(256) void prep_kernel(
    const float* __restrict__ x, const float* __restrict__ pw1,
    const float* __restrict__ vw1, u16* __restrict__ Wp,
    float* __restrict__ partial) {
  const int tid = threadIdx.x;
  if (blockIdx.x >= 64) {
    // ---- pack branch ----
    const int id = (blockIdx.x - 64) * 256 + tid;  // < 49152
    const int g = id / 1536;
    const int rem = id - g * 1536;
    const int kt = rem >> 9;
    const int ctl = (rem >> 6) & 7;
    const int lq = (rem >> 4) & 3;
    const int lm = rem & 15;
    const int p = kt * 4 + lq;
    const int col = ctl * 16 + lm;
    union { u16 s[8]; uint4 v; } pk;
#pragma unroll
    for (int j = 0; j < 8; ++j) {
      int r = (g * 8 + j) * 12 + p;
      float w = (col < 64) ? pw1[r * 64 + col] : vw1[r * 64 + (col - 64)];
      pk.s[j] = f2bf(w);
    }
    *(uint4*)&Wp[(size_t)id * 8] = pk.v;
    return;
  }
  // ---- stats branch: 512 boards, 4 passes of 128 ----
  __shared__ float xb[128 * 44];
  const int bid = blockIdx.x;
  if (tid < 128) { xb[tid * 44 + 42] = 0.f; xb[tid * 44 + 43] = 0.f; }
  const int ti = tid / 22, tj = tid - (tid / 22) * 22;  // 11 x 22 = 242
  const int i0 = ti * 4, j0 = tj * 2;
  float acc[4][2];
#pragma unroll
  for (int i = 0; i < 4; ++i) { acc[i][0] = 0.f; acc[i][1] = 0.f; }
  float msum = 0.f;
  for (int pass = 0; pass < 4; ++pass) {
    if (pass) __syncthreads();
    const float4* src =
        (const float4*)(x + (size_t)(bid * 4 + pass) * 128 * 42);
    for (int i = tid; i < 1344; i += 256) {
      float4 v = src[i];
      float vals[4] = {v.x, v.y, v.z, v.w};
#pragma unroll
      for (int e = 0; e < 4; ++e) {
        int idx = i * 4 + e;
        int b = idx / 42;
        int pos = idx - b * 42;
        xb[b * 44 + pos] = vals[e];
      }
    }
    __syncthreads();
    if (tid < 242) {
      for (int b = 0; b < 128; ++b) {
        f32x4 va = *(const f32x4*)&xb[b * 44 + i0];
        float vb0 = xb[b * 44 + j0], vb1 = xb[b * 44 + j0 + 1];
#pragma unroll
        for (int i = 0; i < 4; ++i) {
          acc[i][0] = fmaf(va[i], vb0, acc[i][0]);
          acc[i][1] = fmaf(va[i], vb1, acc[i][1]);
        }
      }
    }
    if (tid < 42) {
      float a = 0.f;
      for (int b = 0; b < 128; ++b) a += xb[b * 44 + tid];
      msum += a;
    }
  }
  float* outp = partial + (size_t)bid * 1856;
  if (tid < 242) {
#pragma unroll
    for (int i = 0; i < 4; ++i)
#pragma unroll
      for (int j = 0; j < 2; ++j) {
        int gi = i0 + i, gj = j0 + j;
        if (gi < 42 && gj < 42) outp[42 + gi * 42 + gj] = acc[i][j];
      }
  }
  if (tid < 42) outp[tid] = msum;
}

// ---------------------------------------------------------------------------
// stats2: reduce 64 partials + BN-affine coefficients A (scale), D (shift).
// ---------------------------------------------------------------------------
__global__ __launch_bounds__(256) void stats2_kernel(
    const float* __restrict__ partial, const float* __restrict__ convw,
    const float* __restrict__ convb, const float* __restrict__ gamma,
    const float* __restrict__ beta, float* __restrict__ AD) {
  __shared__ float sM[42];
  __shared__ float sS[42 * 42];
  const int tid = threadIdx.x;
  const float invB = 1.f / (float)B_TOTAL;
  for (int idx = tid; idx < 1806; idx += 256) {
    float a = 0.f;
    for (int b = 0; b < 64; ++b) a += partial[(size_t)b * 1856 + idx];
    float v = a * invB;
    if (idx < 42) sM[idx] = v; else sS[idx - 42] = v;
  }
  __syncthreads();
  float w[16];
#pragma unroll
  for (int k = 0; k < 16; ++k) w[k] = convw[tid * 16 + k];
  const float cb = convb[tid];
  float accm = 0.f, acc2 = 0.f;
  for (int p = 0; p < 12; ++p) {
    const int pi = p >> 2, pj = p & 3;
    int idx[16];
#pragma unroll
    for (int k = 0; k < 16; ++k) idx[k] = (pi + (k >> 2)) * 7 + pj + (k & 3);
    float dm = 0.f, q = 0.f;
#pragma unroll
    for (int k = 0; k < 16; ++k) {
      dm = fmaf(w[k], sM[idx[k]], dm);
      float t = 0.f;
      const float* Srow = &sS[idx[k] * 42];
#pragma unroll
      for (int k2 = 0; k2 < 16; ++k2) t = fmaf(w[k2], Srow[idx[k2]], t);
      q = fmaf(w[k], t, q);
    }
    accm += dm;
    acc2 += cb * cb + 2.f * cb * dm + q;
  }
  const float meanY = cb + accm * (1.f / 12.f);
  const float EY2 = acc2 * (1.f / 12.f);
  float var = EY2 - meanY * meanY;
  var = fmaxf(var, 0.f);
  const float alpha = gamma[tid] * rsqrtf(var + EPS);
  AD[tid] = alpha;
  AD[NCH + tid] = beta[tid] + alpha * (cb - meanY);
}

// ---------------------------------------------------------------------------
// fused: conv-MFMA + BN affine + relu -> swizzled Apack -> MFMA GEMM with
// B direct from L2 (register prefetch) -> heads.
// Apack layout: byte = par*12288 + kt*4096 + board*64 + slot*16 + h*8,
//   slot = (kq ^ (board>>2)) & 3  -> A-frag b128 reads are a permutation of a
//   contiguous 1KB block (conflict-free); conv b64 writes ~2-way.
// ---------------------------------------------------------------------------
struct S1 {
  u16 Bpatch[96 * 16 * 8];                                   // 24576 B
  float ADs[512];                                            // 2048 B
  union { float boards[TB * 43]; u16 Apack[12288]; } u;      // 24576 B
};
struct S2 {
  float act[TB * 132];
  float p2v2[TB * 65];
};
union Sh { S1 s1; S2 s2; };

__global__ __launch_bounds__(256, 2) void fused_kernel(
    const float* __restrict__ x, const float* __restrict__ convw,
    const float* __restrict__ AD, const u16* __restrict__ Wp,
    const float* __restrict__ pb1, const float* __restrict__ vb1,
    const float* __restrict__ pw2, const float* __restrict__ pb2,
    const float* __restrict__ pw3, const float* __restrict__ pb3,
    const float* __restrict__ vw2, const float* __restrict__ vb2,
    const float* __restrict__ vw3, const float* __restrict__ vb3,
    float* __restrict__ out) {
  __shared__ Sh sh;
  const int tid = threadIdx.x;
  const int bid = blockIdx.x;
  const int l = tid & 63, wv = tid >> 6;
  const int lm = l & 15, lq = l >> 4;
  const uint4* Wp4 = (const uint4*)Wp;

  // stage boards into padded LDS (region later reused as Apack)
  {
    const float4* src = (const float4*)(x + (size_t)bid * (TB * 42));
    for (int i = tid; i < (TB * 42) / 4; i += 256) {
      float4 v = src[i];
      float vals[4] = {v.x, v.y, v.z, v.w};
#pragma unroll
      for (int e = 0; e < 4; ++e) {
        int idx = i * 4 + e;
        int b = idx / 42;
        int pos = idx - b * 42;
        sh.s1.u.boards[b * 43 + pos] = vals[e];
      }
    }
  }
  sh.s1.ADs[tid] = AD[tid];
  sh.s1.ADs[256 + tid] = AD[256 + tid];
  __syncthreads();

  // build conv patch B-fragments in LDS (once)
#pragma unroll
  for (int i = 0; i < 6; ++i) {
    int s = i * 256 + tid;
    int plm = s & 15, lq2 = (s >> 4) & 1, nt = s >> 5;
    int p = nt >> 2, b = ((nt & 3) << 4) | plm;
    int pi = p >> 2, pj = p & 3;
    const float* bd = &sh.s1.u.boards[b * 43 + (pi + lq2 * 2) * 7 + pj];
    union { u16 s8[8]; uint4 q; } pk;
#pragma unroll
    for (int d = 0; d < 4; ++d) {
      pk.s8[d] = f2bf(bd[d]);
      pk.s8[4 + d] = f2bf(bd[7 + d]);
    }
    *(uint4*)&sh.s1.Bpatch[(size_t)((nt * 2 + lq2) * 16 + plm) * 8] = pk.q;
  }
  __syncthreads();  // boards fully consumed; Apack region free

  // patch fragments -> registers (gg-invariant). lq>=2 duplicates lq&1 rows
  // (finite data; multiplied by zero A-weights).
  uint4 bp[12];
#pragma unroll
  for (int i = 0; i < 12; ++i) {
    int nt = i * 4 + wv;
    bp[i] = *(const uint4*)&sh.s1.Bpatch[(size_t)((nt * 2 + (lq & 1)) * 16 + lm) * 8];
  }

  f32x4 acc[4][2];
#pragma unroll
  for (int R = 0; R < 4; ++R)
#pragma unroll
    for (int t = 0; t < 2; ++t)
#pragma unroll
      for (int r = 0; r < 4; ++r) acc[R][t][r] = 0.f;

  const int parw = lq >> 1, hw = lq & 1;

#pragma unroll 1
  for (int gg = 0; gg < 16; ++gg) {
    if (gg) __syncthreads();  // prev GEMM done reading Apack

    // prefetch B(par=0) = group 2gg  (consumed after mid-barrier)
    uint4 B0[6];
#pragma unroll
    for (int K = 0; K < 3; ++K)
#pragma unroll
      for (int t = 0; t < 2; ++t)
        B0[K * 2 + t] =
            Wp4[(size_t)(2 * gg) * 1536 + K * 512 + (wv * 2 + t) * 64 + l];

    // conv via MFMA: 16 channels (gg*16..+15), K=16 live of K=32
    {
      const int chan = gg * 16 + lm;
      union { u16 s8[8]; short8 v; } aw;
      if (lq < 2) {
        const float* wsrc = convw + chan * 16 + lq * 8;
#pragma unroll
        for (int t2 = 0; t2 < 8; ++t2) aw.s8[t2] = f2bf(wsrc[t2]);
      } else {
#pragma unroll
        for (int t2 = 0; t2 < 8; ++t2) aw.s8[t2] = 0;
      }
      const f32x4 A4 = *(const f32x4*)&sh.s1.ADs[gg * 16 + lq * 4];
      const f32x4 D4 = *(const f32x4*)&sh.s1.ADs[256 + gg * 16 + lq * 4];
#pragma unroll
      for (int i = 0; i < 12; ++i) {
        f32x4 c = {0.f, 0.f, 0.f, 0.f};
        c = __builtin_amdgcn_mfma_f32_16x16x32_bf16(aw.v, u4s8(bp[i]), c, 0, 0, 0);
        union { u16 s4[4]; uint2 q; } hp;
#pragma unroll
        for (int r = 0; r < 4; ++r)
          hp.s4[r] = f2bf(fmaxf(fmaf(c[r], A4[r], D4[r]), 0.f));
        const int slot = ((i & 3) ^ (lm >> 2)) & 3;
        const int off = parw * 12288 + (i >> 2) * 4096 + (wv * 16 + lm) * 64 +
                        slot * 16 + hw * 8;
        *(uint2*)((char*)sh.s1.u.Apack + off) = hp.q;
      }
    }
    __syncthreads();  // Apack ready

    // prefetch B(par=1) = group 2gg+1 (consumed ~24 mfma later, no barrier)
    uint4 B1[6];
#pragma unroll
    for (int K = 0; K < 3; ++K)
#pragma unroll
      for (int t = 0; t < 2; ++t)
        B1[K * 2 + t] =
            Wp4[(size_t)(2 * gg + 1) * 1536 + K * 512 + (wv * 2 + t) * 64 + l];

    const int aslot = ((lq ^ (lm >> 2)) & 3) * 16;
#pragma unroll
    for (int par = 0; par < 2; ++par) {
#pragma unroll
      for (int K = 0; K < 3; ++K) {
        short8 af[4];
#pragma unroll
        for (int R = 0; R < 4; ++R)
          af[R] = *(const short8*)((const char*)sh.s1.u.Apack +
                                   (par * 12288 + K * 4096 +
                                    (R * 16 + lm) * 64 + aslot));
#pragma unroll
        for (int R = 0; R < 4; ++R) {
          acc[R][0] = __builtin_amdgcn_mfma_f32_16x16x32_bf16(
              af[R], u4s8(par ? B1[K * 2 + 0] : B0[K * 2 + 0]), acc[R][0], 0, 0, 0);
          acc[R][1] = __builtin_amdgcn_mfma_f32_16x16x32_bf16(
              af[R], u4s8(par ? B1[K * 2 + 1] : B0[K * 2 + 1]), acc[R][1], 0, 0, 0);
        }
      }
    }
  }
  __syncthreads();  // all GEMM reads done; LDS reused as S2

  // epilogue: bias + relu -> act LDS (cols 0..63 policy, 64..127 value)
  {
    const int n0 = wv * 32 + lm;
    const int n1 = n0 + 16;
    const float b0 = (n0 < 64) ? pb1[n0] : vb1[n0 - 64];
    const float b1 = (n1 < 64) ? pb1[n1] : vb1[n1 - 64];
#pragma unroll
    for (int R = 0; R < 4; ++R)
#pragma unroll
      for (int r = 0; r < 4; ++r) {
        int row = R * 16 + lq * 4 + r;
        sh.s2.act[row * 132 + n0] = fmaxf(acc[R][0][r] + b0, 0.f);
        sh.s2.act[row * 132 + n1] = fmaxf(acc[R][1][r] + b1, 0.f);
      }
  }
  __syncthreads();

  // layer 2: 64 -> 32 both heads; 4 threads per board, 8 neurons each
  {
    const int b = tid >> 2, q = tid & 3;
    float accp[8], accv[8];
#pragma unroll
    for (int n = 0; n < 8; ++n) {
      accp[n] = pb2[q * 8 + n];
      accv[n] = vb2[q * 8 + n];
    }
    const float* actp = &sh.s2.act[b * 132];
    for (int m = 0; m < 64; ++m) {
      float hp = actp[m];
      float hv = actp[64 + m];
      float4 wp0 = *(const float4*)&pw2[m * 32 + q * 8];
      float4 wp1 = *(const float4*)&pw2[m * 32 + q * 8 + 4];
      float4 wv0 = *(const float4*)&vw2[m * 32 + q * 8];
      float4 wv1 = *(const float4*)&vw2[m * 32 + q * 8 + 4];
      accp[0] = fmaf(hp, wp0.x, accp[0]); accp[1] = fmaf(hp, wp0.y, accp[1]);
      accp[2] = fmaf(hp, wp0.z, accp[2]); accp[3] = fmaf(hp, wp0.w, accp[3]);
      accp[4] = fmaf(hp, wp1.x, accp[4]); accp[5] = fmaf(hp, wp1.y, accp[5]);
      accp[6] = fmaf(hp, wp1.z, accp[6]); accp[7] = fmaf(hp, wp1.w, accp[7]);
      accv[0] = fmaf(hv, wv0.x, accv[0]); accv[1] = fmaf(hv, wv0.y, accv[1]);
      accv[2] = fmaf(hv, wv0.z, accv[2]); accv[3] = fmaf(hv, wv0.w, accv[3]);
      accv[4] = fmaf(hv, wv1.x, accv[4]); accv[5] = fmaf(hv, wv1.y, accv[5]);
      accv[6] = fmaf(hv, wv1.z, accv[6]); accv[7] = fmaf(hv, wv1.w, accv[7]);
    }
    float* dst = &sh.s2.p2v2[b * 65];
#pragma unroll
    for (int n = 0; n < 8; ++n) {
      dst[q * 8 + n] = fmaxf(accp[n], 0.f);
      dst[32 + q * 8 + n] = fmaxf(accv[n], 0.f);
    }
  }
  __syncthreads();

  // layer 3 + softmax / tanh: one thread per board
  if (tid < TB) {
    const float* pv = &sh.s2.p2v2[tid * 65];
    float lg[7];
#pragma unroll
    for (int j = 0; j < 7; ++j) lg[j] = pb3[j];
    for (int n = 0; n < 32; ++n) {
      float t = pv[n];
#pragma unroll
      for (int j = 0; j < 7; ++j) lg[j] = fmaf(t, pw3[n * 7 + j], lg[j]);
    }
    float mx = lg[0];
#pragma unroll
    for (int j = 1; j < 7; ++j) mx = fmaxf(mx, lg[j]);
    float ex[7], ssum = 0.f;
#pragma unroll
    for (int j = 0; j < 7; ++j) {
      ex[j] = expf(lg[j] - mx);
      ssum += ex[j];
    }
    float inv = 1.f / ssum;
    int bg = bid * TB + tid;
#pragma unroll
    for (int j = 0; j < 7; ++j) out[bg * 7 + j] = ex[j] * inv;
    float va = vb3[0];
#pragma unroll
    for (int n = 0; n < 32; ++n) va = fmaf(pv[32 + n], vw3[n], va);
    out[B_TOTAL * 7 + bg] = tanhf(va);
  }
}

// ---------------------------------------------------------------------------
extern "C" void kernel_launch(void* const* d_in, const int* in_sizes, int n_in,
                              void* d_out, int out_size, void* d_ws, size_t ws_size,
                              hipStream_t stream) {
  const float* x     = (const float*)d_in[0];
  const float* convw = (const float*)d_in[1];
  const float* convb = (const float*)d_in[2];
  const float* gamma = (const float*)d_in[3];
  const float* beta  = (const float*)d_in[4];
  const float* pw1 = (const float*)d_in[5];
  const float* pb1 = (const float*)d_in[6];
  const float* pw2 = (const float*)d_in[7];
  const float* pb2 = (const float*)d_in[8];
  const float* pw3 = (const float*)d_in[9];
  const float* pb3 = (const float*)d_in[10];
  const float* vw1 = (const float*)d_in[11];
  const float* vb1 = (const float*)d_in[12];
  const float* vw2 = (const float*)d_in[13];
  const float* vb2 = (const float*)d_in[14];
  const float* vw3 = (const float*)d_in[15];
  const float* vb3 = (const float*)d_in[16];
  float* out = (float*)d_out;

  float* ws      = (float*)d_ws;
  float* partial = ws;                       // 64*1856 = 118784 f32
  float* AD      = ws + 118784;              // 512 f32
  u16*   Wp      = (u16*)(ws + 119296);      // 393216 bf16, 16B-aligned

  prep_kernel<<<256, 256, 0, stream>>>(x, pw1, vw1, Wp, partial);
  stats2_kernel<<<1, 256, 0, stream>>>(partial, convw, convb, gamma, beta, AD);
  fused_kernel<<<512, 256, 0, stream>>>(x, convw, AD, Wp, pb1, vb1,
                                        pw2, pb2, pw3, pb3, vw2, vb2, vw3, vb3,
                                        out);
}

// Round 5
// 182.838 us; speedup vs baseline: 8.4846x; 1.4760x over previous
//
#include <hip/hip_runtime.h>
#include <math.h>

#define B_TOTAL 32768
#define TB 64
#define NCH 256
#define EPS 1e-5f

typedef unsigned short u16;
typedef __attribute__((ext_vector_type(8))) short short8;
typedef __attribute__((ext_vector_type(4))) float f32x4;

__device__ __forceinline__ u16 f2bf(float f) {
  unsigned int u = __builtin_bit_cast(unsigned int, f);
  u = (u + 0x7fffu + ((u >> 16) & 1u)) >> 16;
  return (u16)u;
}
__device__ __forceinline__ short8 u4s8(uint4 v) {
  return __builtin_bit_cast(short8, v);
}

// ---------------------------------------------------------------------------
// prep: blocks 0..63 = stats (512 boards each, atomicAdd into sums; the last
//       finisher block computes BN-affine A,D inline via the T-matrix trick);
//       blocks 64..255 = weight pack into bf16 B-fragment order.
// ---------------------------------------------------------------------------
__global__ __launch_bounds__(256) void prep_kernel(
    const float* __restrict__ x, const float* __restrict__ pw1,
    const float* __restrict__ vw1, const float* __restrict__ convw,
    const float* __restrict__ convb, const float* __restrict__ gamma,
    const float* __restrict__ beta, u16* __restrict__ Wp,
    float* __restrict__ sums, int* __restrict__ ctr, float* __restrict__ AD) {
  const int tid = threadIdx.x;
  if (blockIdx.x >= 64) {
    // ---- pack branch ----
    const int id = (blockIdx.x - 64) * 256 + tid;  // < 49152
    const int g = id / 1536;
    const int rem = id - g * 1536;
    const int kt = rem >> 9;
    const int ctl = (rem >> 6) & 7;
    const int lq = (rem >> 4) & 3;
    const int lm = rem & 15;
    const int p = kt * 4 + lq;
    const int col = ctl * 16 + lm;
    union { u16 s[8]; uint4 v; } pk;
#pragma unroll
    for (int j = 0; j < 8; ++j) {
      int r = (g * 8 + j) * 12 + p;
      float w = (col < 64) ? pw1[r * 64 + col] : vw1[r * 64 + (col - 64)];
      pk.s[j] = f2bf(w);
    }
    *(uint4*)&Wp[(size_t)id * 8] = pk.v;
    return;
  }
  // ---- stats branch: 512 boards over 4 passes of 128 ----
  __shared__ float xb[128 * 44];
  __shared__ int elect;
  const int bid = blockIdx.x;
  if (tid < 128) { xb[tid * 44 + 42] = 0.f; xb[tid * 44 + 43] = 0.f; }
  const int ti = tid / 22, tj = tid - (tid / 22) * 22;  // 11 x 22 = 242
  const int i0 = ti * 4, j0 = tj * 2;
  float acc[4][2];
#pragma unroll
  for (int i = 0; i < 4; ++i) { acc[i][0] = 0.f; acc[i][1] = 0.f; }
  float msum = 0.f;
  for (int pass = 0; pass < 4; ++pass) {
    if (pass) __syncthreads();
    const float4* src =
        (const float4*)(x + (size_t)(bid * 4 + pass) * 128 * 42);
    for (int i = tid; i < 1344; i += 256) {
      float4 v = src[i];
      float vals[4] = {v.x, v.y, v.z, v.w};
#pragma unroll
      for (int e = 0; e < 4; ++e) {
        int idx = i * 4 + e;
        int b = idx / 42;
        int pos = idx - b * 42;
        xb[b * 44 + pos] = vals[e];
      }
    }
    __syncthreads();
    if (tid < 242) {
      for (int b = 0; b < 128; ++b) {
        f32x4 va = *(const f32x4*)&xb[b * 44 + i0];
        float2 vb = *(const float2*)&xb[b * 44 + j0];
#pragma unroll
        for (int i = 0; i < 4; ++i) {
          acc[i][0] = fmaf(va[i], vb.x, acc[i][0]);
          acc[i][1] = fmaf(va[i], vb.y, acc[i][1]);
        }
      }
    }
    if (tid < 42) {
      float a = 0.f;
      for (int b = 0; b < 128; ++b) a += xb[b * 44 + tid];
      msum += a;
    }
  }
  if (tid < 242) {
#pragma unroll
    for (int i = 0; i < 4; ++i)
#pragma unroll
      for (int j = 0; j < 2; ++j) {
        int gi = i0 + i, gj = j0 + j;
        if (gi < 42 && gj < 42) atomicAdd(&sums[42 + gi * 42 + gj], acc[i][j]);
      }
  }
  if (tid < 42) atomicAdd(&sums[tid], msum);
  __threadfence();
  __syncthreads();
  if (tid == 0) {
    int old = __hip_atomic_fetch_add(ctr, 1, __ATOMIC_ACQ_REL,
                                     __HIP_MEMORY_SCOPE_AGENT);
    elect = (old == 63);
  }
  __syncthreads();
  if (!elect) return;

  // ---- inline stats2 (only the 64th-finishing block) ----
  float* sM = xb;           // 42
  float* sS = xb + 42;      // 42*42
  float* T = xb + 1806;     // 16*16
  float* M16 = xb + 2062;   // 16
  const float invB = 1.f / (float)B_TOTAL;
  for (int idx = tid; idx < 1806; idx += 256) {
    float v = __hip_atomic_load(&sums[idx], __ATOMIC_RELAXED,
                                __HIP_MEMORY_SCOPE_AGENT) * invB;
    if (idx < 42) sM[idx] = v; else sS[idx - 42] = v;
  }
  __syncthreads();
  {
    const int k = tid >> 4, k2 = tid & 15;
    float s = 0.f;
#pragma unroll
    for (int p = 0; p < 12; ++p) {
      int pi = p >> 2, pj = p & 3;
      int i1 = (pi + (k >> 2)) * 7 + pj + (k & 3);
      int i2 = (pi + (k2 >> 2)) * 7 + pj + (k2 & 3);
      s += sS[i1 * 42 + i2];
    }
    T[tid] = s;
    if (tid < 16) {
      float m = 0.f;
#pragma unroll
      for (int p = 0; p < 12; ++p) {
        int pi = p >> 2, pj = p & 3;
        m += sM[(pi + (tid >> 2)) * 7 + pj + (tid & 3)];
      }
      M16[tid] = m;
    }
  }
  __syncthreads();
  {
    float w[16];
#pragma unroll
    for (int k = 0; k < 16; ++k) w[k] = convw[tid * 16 + k];
    const float cb = convb[tid];
    float accm = 0.f, q = 0.f;
#pragma unroll
    for (int k = 0; k < 16; ++k) {
      accm = fmaf(w[k], M16[k], accm);
      float t = 0.f;
#pragma unroll
      for (int k2 = 0; k2 < 16; ++k2) t = fmaf(w[k2], T[k * 16 + k2], t);
      q = fmaf(w[k], t, q);
    }
    const float meanY = cb + accm * (1.f / 12.f);
    const float EY2 = cb * cb + (2.f * cb * accm + q) * (1.f / 12.f);
    float var = EY2 - meanY * meanY;
    var = fmaxf(var, 0.f);
    const float alpha = gamma[tid] * rsqrtf(var + EPS);
    AD[tid] = alpha;
    AD[NCH + tid] = beta[tid] + alpha * (cb - meanY);
  }
}

// ---------------------------------------------------------------------------
// fused: conv-MFMA + BN affine + relu -> lane-linear Apack (ping-pong) ->
// MFMA GEMM (B from L2) -> MFMA head layer2 -> layer3/softmax/tanh.
// Apack: addr(par,K,R) = ((par*3+K)*4+R)*1024; lane l reads [addr + l*16]
// (canonical linear ds_read_b128, conflict-free). Conv writes two contiguous
// 256B runs per instruction (conflict-free b64).
// ---------------------------------------------------------------------------
struct S1 {
  u16 Bpatch[48 * 2 * 16 * 8];                               // 24576 B
  float ADs[512];                                            // 2048 B
  u16 Apk0[12288];                                           // 24576 B
  union { float boards[TB * 43]; u16 Apk1[12288]; } u;       // 24576 B
};
struct S2 {
  float act[TB * 132];
  float p2v2[TB * 65];
};
union Sh { S1 s1; S2 s2; };

__global__ __launch_bounds__(256, 2) void fused_kernel(
    const float* __restrict__ x, const float* __restrict__ convw,
    const float* __restrict__ AD, const u16* __restrict__ Wp,
    const float* __restrict__ pb1, const float* __restrict__ vb1,
    const float* __restrict__ pw2, const float* __restrict__ pb2,
    const float* __restrict__ pw3, const float* __restrict__ pb3,
    const float* __restrict__ vw2, const float* __restrict__ vb2,
    const float* __restrict__ vw3, const float* __restrict__ vb3,
    float* __restrict__ out) {
  __shared__ Sh sh;
  const int tid = threadIdx.x;
  const int bid = blockIdx.x;
  const int l = tid & 63, wv = tid >> 6;
  const int lm = l & 15, lq = l >> 4;
  const uint4* Wp4 = (const uint4*)Wp;

  // stage boards into padded LDS (region later reused as Apk1)
  {
    const float4* src = (const float4*)(x + (size_t)bid * (TB * 42));
    for (int i = tid; i < (TB * 42) / 4; i += 256) {
      float4 v = src[i];
      float vals[4] = {v.x, v.y, v.z, v.w};
#pragma unroll
      for (int e = 0; e < 4; ++e) {
        int idx = i * 4 + e;
        int b = idx / 42;
        int pos = idx - b * 42;
        sh.s1.u.boards[b * 43 + pos] = vals[e];
      }
    }
  }
  sh.s1.ADs[tid] = AD[tid];
  sh.s1.ADs[256 + tid] = AD[256 + tid];
  __syncthreads();

  // build conv patch B-fragments in LDS (once)
#pragma unroll
  for (int i = 0; i < 6; ++i) {
    int s = i * 256 + tid;
    int plm = s & 15, lq2 = (s >> 4) & 1, nt = s >> 5;
    int p = nt >> 2, b = ((nt & 3) << 4) | plm;
    int pi = p >> 2, pj = p & 3;
    const float* bd = &sh.s1.u.boards[b * 43 + (pi + lq2 * 2) * 7 + pj];
    union { u16 s8[8]; uint4 q; } pk;
#pragma unroll
    for (int d = 0; d < 4; ++d) {
      pk.s8[d] = f2bf(bd[d]);
      pk.s8[4 + d] = f2bf(bd[7 + d]);
    }
    *(uint4*)&sh.s1.Bpatch[(size_t)((nt * 2 + lq2) * 16 + plm) * 8] = pk.q;
  }
  __syncthreads();  // boards fully consumed; Apk1 region free after bp load

  // patch fragments -> registers (gp-invariant). lq>=2 duplicates lq&1 rows
  // (finite data; multiplied by zero A-weights).
  uint4 bp[12];
#pragma unroll
  for (int i = 0; i < 12; ++i) {
    int nt = i * 4 + wv;
    bp[i] = *(const uint4*)&sh.s1.Bpatch[(size_t)((nt * 2 + (lq & 1)) * 16 + lm) * 8];
  }

  f32x4 acc[4][2];
#pragma unroll
  for (int R = 0; R < 4; ++R)
#pragma unroll
    for (int t = 0; t < 2; ++t)
#pragma unroll
      for (int r = 0; r < 4; ++r) acc[R][t][r] = 0.f;

  const int parw = lq >> 1, hw = lq & 1;
  char* const apk0 = (char*)sh.s1.Apk0;
  char* const apk1 = (char*)sh.s1.u.Apk1;

  // conv for group-pair gp into buffer: 16 channels, K=16 live of K=32
#define CONV_STEP(gp_, wbuf_)                                                  \
  {                                                                            \
    const int chan = (gp_)*16 + lm;                                            \
    union { u16 s8[8]; short8 v; } aw;                                         \
    if (lq < 2) {                                                              \
      const float* wsrc = convw + chan * 16 + lq * 8;                          \
      _Pragma("unroll") for (int t2 = 0; t2 < 8; ++t2) aw.s8[t2] =             \
          f2bf(wsrc[t2]);                                                      \
    } else {                                                                   \
      _Pragma("unroll") for (int t2 = 0; t2 < 8; ++t2) aw.s8[t2] = 0;          \
    }                                                                          \
    const f32x4 A4 = *(const f32x4*)&sh.s1.ADs[(gp_)*16 + lq * 4];             \
    const f32x4 D4 = *(const f32x4*)&sh.s1.ADs[256 + (gp_)*16 + lq * 4];       \
    _Pragma("unroll") for (int i = 0; i < 12; ++i) {                           \
      const int nt = i * 4 + wv;                                               \
      f32x4 c = {0.f, 0.f, 0.f, 0.f};                                          \
      c = __builtin_amdgcn_mfma_f32_16x16x32_bf16(aw.v, u4s8(bp[i]), c, 0, 0,  \
                                                  0);                          \
      union { u16 s4[4]; uint2 q; } hp;                                        \
      _Pragma("unroll") for (int r = 0; r < 4; ++r) hp.s4[r] =                 \
          f2bf(fmaxf(fmaf(c[r], A4[r], D4[r]), 0.f));                          \
      const int K_ = nt >> 4, kq_ = (nt >> 2) & 3, R_ = nt & 3;                \
      const int off = ((parw * 3 + K_) * 4 + R_) * 1024 +                      \
                      (kq_ * 16 + lm) * 16 + hw * 8;                           \
      *(uint2*)((wbuf_) + off) = hp.q;                                         \
    }                                                                          \
  }

  CONV_STEP(0, apk0);

#pragma unroll 1
  for (int gp = 0; gp < 16; ++gp) {
    __syncthreads();  // Apk[gp&1] written; prev GEMM done with Apk[(gp+1)&1]

    // B fragments for this gp from L2 (lane-linear, coalesced)
    uint4 Bv[12];
#pragma unroll
    for (int par = 0; par < 2; ++par)
#pragma unroll
      for (int K = 0; K < 3; ++K)
#pragma unroll
        for (int t = 0; t < 2; ++t)
          Bv[par * 6 + K * 2 + t] =
              Wp4[(size_t)(2 * gp + par) * 1536 + K * 512 + (wv * 2 + t) * 64 + l];

    // conv for next group-pair into the other buffer (overlaps GEMM below)
    if (gp < 15) {
      char* wbuf = ((gp + 1) & 1) ? apk1 : apk0;
      CONV_STEP(gp + 1, wbuf);
    }

    // GEMM for gp from Apk[gp&1]
    const char* rbuf = (gp & 1) ? apk1 : apk0;
#pragma unroll
    for (int par = 0; par < 2; ++par)
#pragma unroll
      for (int K = 0; K < 3; ++K) {
        short8 af[4];
#pragma unroll
        for (int R = 0; R < 4; ++R)
          af[R] = *(const short8*)(rbuf + ((par * 3 + K) * 4 + R) * 1024 +
                                   l * 16);
#pragma unroll
        for (int R = 0; R < 4; ++R) {
          acc[R][0] = __builtin_amdgcn_mfma_f32_16x16x32_bf16(
              af[R], u4s8(Bv[par * 6 + K * 2 + 0]), acc[R][0], 0, 0, 0);
          acc[R][1] = __builtin_amdgcn_mfma_f32_16x16x32_bf16(
              af[R], u4s8(Bv[par * 6 + K * 2 + 1]), acc[R][1], 0, 0, 0);
        }
      }
  }
  __syncthreads();  // all GEMM reads done; LDS reused as S2

  // epilogue: bias + relu -> act LDS (cols 0..63 policy, 64..127 value)
  {
    const int n0 = wv * 32 + lm;
    const int n1 = n0 + 16;
    const float b0 = (n0 < 64) ? pb1[n0] : vb1[n0 - 64];
    const float b1 = (n1 < 64) ? pb1[n1] : vb1[n1 - 64];
#pragma unroll
    for (int R = 0; R < 4; ++R)
#pragma unroll
      for (int r = 0; r < 4; ++r) {
        int row = R * 16 + lq * 4 + r;
        sh.s2.act[row * 132 + n0] = fmaxf(acc[R][0][r] + b0, 0.f);
        sh.s2.act[row * 132 + n1] = fmaxf(acc[R][1][r] + b1, 0.f);
      }
  }
  __syncthreads();

  // layer 2 via MFMA: boards 64 (wave wv owns R=wv) x 32 neurons x K=64, x2 heads
  {
    f32x4 acc2[2][2];  // [head][ntile]
#pragma unroll
    for (int h = 0; h < 2; ++h)
#pragma unroll
      for (int t = 0; t < 2; ++t)
#pragma unroll
        for (int r = 0; r < 4; ++r) acc2[h][t][r] = 0.f;
#pragma unroll
    for (int h = 0; h < 2; ++h) {
      const float* w2 = h ? vw2 : pw2;
#pragma unroll
      for (int k2 = 0; k2 < 2; ++k2) {
        union { u16 s8[8]; short8 v; } afl;
        const float* ap =
            &sh.s2.act[(wv * 16 + lm) * 132 + h * 64 + k2 * 32 + lq * 8];
        f32x4 a0 = *(const f32x4*)ap;
        f32x4 a1 = *(const f32x4*)(ap + 4);
#pragma unroll
        for (int e = 0; e < 4; ++e) {
          afl.s8[e] = f2bf(a0[e]);
          afl.s8[4 + e] = f2bf(a1[e]);
        }
#pragma unroll
        for (int t = 0; t < 2; ++t) {
          union { u16 s8[8]; short8 v; } bfl;
#pragma unroll
          for (int j = 0; j < 8; ++j)
            bfl.s8[j] = f2bf(w2[(k2 * 32 + lq * 8 + j) * 32 + t * 16 + lm]);
          acc2[h][t] = __builtin_amdgcn_mfma_f32_16x16x32_bf16(
              afl.v, bfl.v, acc2[h][t], 0, 0, 0);
        }
      }
    }
#pragma unroll
    for (int h = 0; h < 2; ++h)
#pragma unroll
      for (int t = 0; t < 2; ++t) {
        const float bias = (h ? vb2 : pb2)[t * 16 + lm];
#pragma unroll
        for (int r = 0; r < 4; ++r) {
          int board = wv * 16 + lq * 4 + r;
          sh.s2.p2v2[board * 65 + h * 32 + t * 16 + lm] =
              fmaxf(acc2[h][t][r] + bias, 0.f);
        }
      }
  }
  __syncthreads();

  // layer 3 + softmax / tanh: one thread per board
  if (tid < TB) {
    const float* pv = &sh.s2.p2v2[tid * 65];
    float lg[7];
#pragma unroll
    for (int j = 0; j < 7; ++j) lg[j] = pb3[j];
    for (int n = 0; n < 32; ++n) {
      float t = pv[n];
#pragma unroll
      for (int j = 0; j < 7; ++j) lg[j] = fmaf(t, pw3[n * 7 + j], lg[j]);
    }
    float mx = lg[0];
#pragma unroll
    for (int j = 1; j < 7; ++j) mx = fmaxf(mx, lg[j]);
    float ex[7], ssum = 0.f;
#pragma unroll
    for (int j = 0; j < 7; ++j) {
      ex[j] = expf(lg[j] - mx);
      ssum += ex[j];
    }
    float inv = 1.f / ssum;
    int bg = bid * TB + tid;
#pragma unroll
    for (int j = 0; j < 7; ++j) out[bg * 7 + j] = ex[j] * inv;
    float va = vb3[0];
#pragma unroll
    for (int n = 0; n < 32; ++n) va = fmaf(pv[32 + n], vw3[n], va);
    out[B_TOTAL * 7 + bg] = tanhf(va);
  }
}

// ---------------------------------------------------------------------------
extern "C" void kernel_launch(void* const* d_in, const int* in_sizes, int n_in,
                              void* d_out, int out_size, void* d_ws, size_t ws_size,
                              hipStream_t stream) {
  const float* x     = (const float*)d_in[0];
  const float* convw = (const float*)d_in[1];
  const float* convb = (const float*)d_in[2];
  const float* gamma = (const float*)d_in[3];
  const float* beta  = (const float*)d_in[4];
  const float* pw1 = (const float*)d_in[5];
  const float* pb1 = (const float*)d_in[6];
  const float* pw2 = (const float*)d_in[7];
  const float* pb2 = (const float*)d_in[8];
  const float* pw3 = (const float*)d_in[9];
  const float* pb3 = (const float*)d_in[10];
  const float* vw1 = (const float*)d_in[11];
  const float* vb1 = (const float*)d_in[12];
  const float* vw2 = (const float*)d_in[13];
  const float* vb2 = (const float*)d_in[14];
  const float* vw3 = (const float*)d_in[15];
  const float* vb3 = (const float*)d_in[16];
  float* out = (float*)d_out;

  float* ws   = (float*)d_ws;
  float* sums = ws;                     // 1806 f32
  int*   ctr  = (int*)(ws + 1806);      // 1 int
  float* AD   = ws + 1808;              // 512 f32
  u16*   Wp   = (u16*)(ws + 2320);      // 393216 bf16, 16B-aligned

  hipMemsetAsync(ws, 0, 1807 * sizeof(float), stream);
  prep_kernel<<<256, 256, 0, stream>>>(x, pw1, vw1, convw, convb, gamma, beta,
                                       Wp, sums, ctr, AD);
  fused_kernel<<<512, 256, 0, stream>>>(x, convw, AD, Wp, pb1, vb1,
                                        pw2, pb2, pw3, pb3, vw2, vb2, vw3, vb3,
                                        out);
}

// Round 8
// 171.565 us; speedup vs baseline: 9.0421x; 1.0657x over previous
//
#include <hip/hip_runtime.h>
#include <math.h>

#define B_TOTAL 32768
#define TB 64
#define NCH 256
#define EPS 1e-5f

typedef unsigned short u16;
typedef __attribute__((ext_vector_type(8))) short short8;
typedef __attribute__((ext_vector_type(4))) float f32x4;

__device__ __forceinline__ u16 f2bf(float f) {  // RNE
  unsigned int u = __builtin_bit_cast(unsigned int, f);
  u = (u + 0x7fffu + ((u >> 16) & 1u)) >> 16;
  return (u16)u;
}
__device__ __forceinline__ short8 u4s8(uint4 v) {
  return __builtin_bit_cast(short8, v);
}

// ---------------------------------------------------------------------------
// prep (257 blocks) — R7 version (bisection: suspect set A/B/C):
//   0..127   stats: 256 boards each (2 passes), atomicAdd into sums; 128th
//            finisher computes BN-affine A,D inline (T-matrix reduction).
//   128..255 pack [pw1|vw1] -> Wp (bf16 B-fragment order), 384 chunks each.
//   256      pack [pw2|vw2] -> Wp2 (written but UNUSED this round).
// ---------------------------------------------------------------------------
__global__ __launch_bounds__(256) void prep_kernel(
    const float* __restrict__ x, const float* __restrict__ pw1,
    const float* __restrict__ vw1, const float* __restrict__ pw2,
    const float* __restrict__ vw2, const float* __restrict__ convw,
    const float* __restrict__ convb, const float* __restrict__ gamma,
    const float* __restrict__ beta, u16* __restrict__ Wp,
    u16* __restrict__ Wp2, float* __restrict__ sums, int* __restrict__ ctr,
    float* __restrict__ AD) {
  const int tid = threadIdx.x;
  if (blockIdx.x == 256) {
#pragma unroll
    for (int k = 0; k < 2; ++k) {
      const int id = k * 256 + tid;  // < 512
      const int lm = id & 15, lq = (id >> 4) & 3, t = (id >> 6) & 1;
      const int k2 = (id >> 7) & 1, h = (id >> 8) & 1;
      const float* w2 = h ? vw2 : pw2;
      union { u16 s[8]; uint4 v; } pk;
#pragma unroll
      for (int j = 0; j < 8; ++j)
        pk.s[j] = f2bf(w2[(k2 * 32 + lq * 8 + j) * 32 + t * 16 + lm]);
      *(uint4*)&Wp2[(size_t)id * 8] = pk.v;
    }
    return;
  }
  if (blockIdx.x >= 128) {
    const int base = (blockIdx.x - 128) * 384;
#pragma unroll
    for (int k = 0; k < 2; ++k) {
      const int s = k * 256 + tid;
      if (s >= 384) break;
      const int id = base + s;  // < 49152
      const int g = id / 1536;
      const int rem = id - g * 1536;
      const int kt = rem >> 9;
      const int ctl = (rem >> 6) & 7;
      const int lq = (rem >> 4) & 3;
      const int lm = rem & 15;
      const int p = kt * 4 + lq;
      const int col = ctl * 16 + lm;
      union { u16 s[8]; uint4 v; } pk;
#pragma unroll
      for (int j = 0; j < 8; ++j) {
        int r = (g * 8 + j) * 12 + p;
        float w = (col < 64) ? pw1[r * 64 + col] : vw1[r * 64 + (col - 64)];
        pk.s[j] = f2bf(w);
      }
      *(uint4*)&Wp[(size_t)id * 8] = pk.v;
    }
    return;
  }
  // ---- stats branch: 256 boards over 2 passes of 128 ----
  __shared__ float xb[128 * 44];
  __shared__ int elect;
  const int bid = blockIdx.x;
  if (tid < 128) { xb[tid * 44 + 42] = 0.f; xb[tid * 44 + 43] = 0.f; }
  const int ti = tid / 22, tj = tid - (tid / 22) * 22;  // 11 x 22 = 242
  const int i0 = ti * 4, j0 = tj * 2;
  float acc[4][2];
#pragma unroll
  for (int i = 0; i < 4; ++i) { acc[i][0] = 0.f; acc[i][1] = 0.f; }
  float msum = 0.f;
  for (int pass = 0; pass < 2; ++pass) {
    if (pass) __syncthreads();
    const float4* src =
        (const float4*)(x + (size_t)(bid * 2 + pass) * 128 * 42);
    for (int i = tid; i < 1344; i += 256) {
      float4 v = src[i];
      float vals[4] = {v.x, v.y, v.z, v.w};
#pragma unroll
      for (int e = 0; e < 4; ++e) {
        int idx = i * 4 + e;
        int b = idx / 42;
        int pos = idx - b * 42;
        xb[b * 44 + pos] = vals[e];
      }
    }
    __syncthreads();
    if (tid < 242) {
      for (int b = 0; b < 128; ++b) {
        f32x4 va = *(const f32x4*)&xb[b * 44 + i0];
        float2 vb = *(const float2*)&xb[b * 44 + j0];
#pragma unroll
        for (int i = 0; i < 4; ++i) {
          acc[i][0] = fmaf(va[i], vb.x, acc[i][0]);
          acc[i][1] = fmaf(va[i], vb.y, acc[i][1]);
        }
      }
    }
    if (tid < 42) {
      float a = 0.f;
      for (int b = 0; b < 128; ++b) a += xb[b * 44 + tid];
      msum += a;
    }
  }
  if (tid < 242) {
#pragma unroll
    for (int i = 0; i < 4; ++i)
#pragma unroll
      for (int j = 0; j < 2; ++j) {
        int gi = i0 + i, gj = j0 + j;
        if (gi < 42 && gj < 42) atomicAdd(&sums[42 + gi * 42 + gj], acc[i][j]);
      }
  }
  if (tid < 42) atomicAdd(&sums[tid], msum);
  __threadfence();
  __syncthreads();
  if (tid == 0) {
    int old = __hip_atomic_fetch_add(ctr, 1, __ATOMIC_ACQ_REL,
                                     __HIP_MEMORY_SCOPE_AGENT);
    elect = (old == 127);
  }
  __syncthreads();
  if (!elect) return;

  // ---- inline stats2 (only the 128th-finishing block) ----
  float* sM = xb;           // 42
  float* sS = xb + 42;      // 42*42
  float* T = xb + 1806;     // 16*16
  float* M16 = xb + 2062;   // 16
  const float invB = 1.f / (float)B_TOTAL;
  for (int idx = tid; idx < 1806; idx += 256) {
    float v = __hip_atomic_load(&sums[idx], __ATOMIC_RELAXED,
                                __HIP_MEMORY_SCOPE_AGENT) * invB;
    if (idx < 42) sM[idx] = v; else sS[idx - 42] = v;
  }
  __syncthreads();
  {
    const int k = tid >> 4, k2 = tid & 15;
    float s = 0.f;
#pragma unroll
    for (int p = 0; p < 12; ++p) {
      int pi = p >> 2, pj = p & 3;
      int i1 = (pi + (k >> 2)) * 7 + pj + (k & 3);
      int i2 = (pi + (k2 >> 2)) * 7 + pj + (k2 & 3);
      s += sS[i1 * 42 + i2];
    }
    T[tid] = s;
    if (tid < 16) {
      float m = 0.f;
#pragma unroll
      for (int p = 0; p < 12; ++p) {
        int pi = p >> 2, pj = p & 3;
        m += sM[(pi + (tid >> 2)) * 7 + pj + (tid & 3)];
      }
      M16[tid] = m;
    }
  }
  __syncthreads();
  {
    float w[16];
#pragma unroll
    for (int k = 0; k < 16; ++k) w[k] = convw[tid * 16 + k];
    const float cb = convb[tid];
    float accm = 0.f, q = 0.f;
#pragma unroll
    for (int k = 0; k < 16; ++k) {
      accm = fmaf(w[k], M16[k], accm);
      float t = 0.f;
#pragma unroll
      for (int k2 = 0; k2 < 16; ++k2) t = fmaf(w[k2], T[k * 16 + k2], t);
      q = fmaf(w[k], t, q);
    }
    const float meanY = cb + accm * (1.f / 12.f);
    const float EY2 = cb * cb + (2.f * cb * accm + q) * (1.f / 12.f);
    float var = EY2 - meanY * meanY;
    var = fmaxf(var, 0.f);
    const float alpha = gamma[tid] * rsqrtf(var + EPS);
    AD[tid] = alpha;
    AD[NCH + tid] = beta[tid] + alpha * (cb - meanY);
  }
}

// ---------------------------------------------------------------------------
// fused — VERBATIM R5 (passing, 53.9 µs): conv-MFMA -> lane-linear Apack
// (ping-pong) -> MFMA GEMM (B from L2) -> MFMA layer2 (inline w2 frags) ->
// serial layer3.
// ---------------------------------------------------------------------------
struct S1 {
  u16 Bpatch[48 * 2 * 16 * 8];                               // 24576 B
  float ADs[512];                                            // 2048 B
  u16 Apk0[12288];                                           // 24576 B
  union { float boards[TB * 43]; u16 Apk1[12288]; } u;       // 24576 B
};
struct S2 {
  float act[TB * 132];
  float p2v2[TB * 65];
};
union Sh { S1 s1; S2 s2; };

__global__ __launch_bounds__(256, 2) void fused_kernel(
    const float* __restrict__ x, const float* __restrict__ convw,
    const float* __restrict__ AD, const u16* __restrict__ Wp,
    const float* __restrict__ pb1, const float* __restrict__ vb1,
    const float* __restrict__ pw2, const float* __restrict__ pb2,
    const float* __restrict__ pw3, const float* __restrict__ pb3,
    const float* __restrict__ vw2, const float* __restrict__ vb2,
    const float* __restrict__ vw3, const float* __restrict__ vb3,
    float* __restrict__ out) {
  __shared__ Sh sh;
  const int tid = threadIdx.x;
  const int bid = blockIdx.x;
  const int l = tid & 63, wv = tid >> 6;
  const int lm = l & 15, lq = l >> 4;
  const uint4* Wp4 = (const uint4*)Wp;

  // stage boards into padded LDS (region later reused as Apk1)
  {
    const float4* src = (const float4*)(x + (size_t)bid * (TB * 42));
    for (int i = tid; i < (TB * 42) / 4; i += 256) {
      float4 v = src[i];
      float vals[4] = {v.x, v.y, v.z, v.w};
#pragma unroll
      for (int e = 0; e < 4; ++e) {
        int idx = i * 4 + e;
        int b = idx / 42;
        int pos = idx - b * 42;
        sh.s1.u.boards[b * 43 + pos] = vals[e];
      }
    }
  }
  sh.s1.ADs[tid] = AD[tid];
  sh.s1.ADs[256 + tid] = AD[256 + tid];
  __syncthreads();

  // build conv patch B-fragments in LDS (once)
#pragma unroll
  for (int i = 0; i < 6; ++i) {
    int s = i * 256 + tid;
    int plm = s & 15, lq2 = (s >> 4) & 1, nt = s >> 5;
    int p = nt >> 2, b = ((nt & 3) << 4) | plm;
    int pi = p >> 2, pj = p & 3;
    const float* bd = &sh.s1.u.boards[b * 43 + (pi + lq2 * 2) * 7 + pj];
    union { u16 s8[8]; uint4 q; } pk;
#pragma unroll
    for (int d = 0; d < 4; ++d) {
      pk.s8[d] = f2bf(bd[d]);
      pk.s8[4 + d] = f2bf(bd[7 + d]);
    }
    *(uint4*)&sh.s1.Bpatch[(size_t)((nt * 2 + lq2) * 16 + plm) * 8] = pk.q;
  }
  __syncthreads();  // boards fully consumed; Apk1 region free after bp load

  // patch fragments -> registers (gp-invariant). lq>=2 duplicates lq&1 rows
  // (finite data; multiplied by zero A-weights).
  uint4 bp[12];
#pragma unroll
  for (int i = 0; i < 12; ++i) {
    int nt = i * 4 + wv;
    bp[i] = *(const uint4*)&sh.s1.Bpatch[(size_t)((nt * 2 + (lq & 1)) * 16 + lm) * 8];
  }

  f32x4 acc[4][2];
#pragma unroll
  for (int R = 0; R < 4; ++R)
#pragma unroll
    for (int t = 0; t < 2; ++t)
#pragma unroll
      for (int r = 0; r < 4; ++r) acc[R][t][r] = 0.f;

  const int parw = lq >> 1, hw = lq & 1;
  char* const apk0 = (char*)sh.s1.Apk0;
  char* const apk1 = (char*)sh.s1.u.Apk1;

  // conv for group-pair gp into buffer: 16 channels, K=16 live of K=32
#define CONV_STEP(gp_, wbuf_)                                                  \
  {                                                                            \
    const int chan = (gp_)*16 + lm;                                            \
    union { u16 s8[8]; short8 v; } aw;                                         \
    if (lq < 2) {                                                              \
      const float* wsrc = convw + chan * 16 + lq * 8;                          \
      _Pragma("unroll") for (int t2 = 0; t2 < 8; ++t2) aw.s8[t2] =             \
          f2bf(wsrc[t2]);                                                      \
    } else {                                                                   \
      _Pragma("unroll") for (int t2 = 0; t2 < 8; ++t2) aw.s8[t2] = 0;          \
    }                                                                          \
    const f32x4 A4 = *(const f32x4*)&sh.s1.ADs[(gp_)*16 + lq * 4];             \
    const f32x4 D4 = *(const f32x4*)&sh.s1.ADs[256 + (gp_)*16 + lq * 4];       \
    _Pragma("unroll") for (int i = 0; i < 12; ++i) {                           \
      const int nt = i * 4 + wv;                                               \
      f32x4 c = {0.f, 0.f, 0.f, 0.f};                                          \
      c = __builtin_amdgcn_mfma_f32_16x16x32_bf16(aw.v, u4s8(bp[i]), c, 0, 0,  \
                                                  0);                          \
      union { u16 s4[4]; uint2 q; } hp;                                        \
      _Pragma("unroll") for (int r = 0; r < 4; ++r) hp.s4[r] =                 \
          f2bf(fmaxf(fmaf(c[r], A4[r], D4[r]), 0.f));                          \
      const int K_ = nt >> 4, kq_ = (nt >> 2) & 3, R_ = nt & 3;                \
      const int off = ((parw * 3 + K_) * 4 + R_) * 1024 +                      \
                      (kq_ * 16 + lm) * 16 + hw * 8;                           \
      *(uint2*)((wbuf_) + off) = hp.q;                                         \
    }                                                                          \
  }

  CONV_STEP(0, apk0);

#pragma unroll 1
  for (int gp = 0; gp < 16; ++gp) {
    __syncthreads();  // Apk[gp&1] written; prev GEMM done with Apk[(gp+1)&1]

    // B fragments for this gp from L2 (lane-linear, coalesced)
    uint4 Bv[12];
#pragma unroll
    for (int par = 0; par < 2; ++par)
#pragma unroll
      for (int K = 0; K < 3; ++K)
#pragma unroll
        for (int t = 0; t < 2; ++t)
          Bv[par * 6 + K * 2 + t] =
              Wp4[(size_t)(2 * gp + par) * 1536 + K * 512 + (wv * 2 + t) * 64 + l];

    // conv for next group-pair into the other buffer (overlaps GEMM below)
    if (gp < 15) {
      char* wbuf = ((gp + 1) & 1) ? apk1 : apk0;
      CONV_STEP(gp + 1, wbuf);
    }

    // GEMM for gp from Apk[gp&1]
    const char* rbuf = (gp & 1) ? apk1 : apk0;
#pragma unroll
    for (int par = 0; par < 2; ++par)
#pragma unroll
      for (int K = 0; K < 3; ++K) {
        short8 af[4];
#pragma unroll
        for (int R = 0; R < 4; ++R)
          af[R] = *(const short8*)(rbuf + ((par * 3 + K) * 4 + R) * 1024 +
                                   l * 16);
#pragma unroll
        for (int R = 0; R < 4; ++R) {
          acc[R][0] = __builtin_amdgcn_mfma_f32_16x16x32_bf16(
              af[R], u4s8(Bv[par * 6 + K * 2 + 0]), acc[R][0], 0, 0, 0);
          acc[R][1] = __builtin_amdgcn_mfma_f32_16x16x32_bf16(
              af[R], u4s8(Bv[par * 6 + K * 2 + 1]), acc[R][1], 0, 0, 0);
        }
      }
  }
  __syncthreads();  // all GEMM reads done; LDS reused as S2

  // epilogue: bias + relu -> act LDS (cols 0..63 policy, 64..127 value)
  {
    const int n0 = wv * 32 + lm;
    const int n1 = n0 + 16;
    const float b0 = (n0 < 64) ? pb1[n0] : vb1[n0 - 64];
    const float b1 = (n1 < 64) ? pb1[n1] : vb1[n1 - 64];
#pragma unroll
    for (int R = 0; R < 4; ++R)
#pragma unroll
      for (int r = 0; r < 4; ++r) {
        int row = R * 16 + lq * 4 + r;
        sh.s2.act[row * 132 + n0] = fmaxf(acc[R][0][r] + b0, 0.f);
        sh.s2.act[row * 132 + n1] = fmaxf(acc[R][1][r] + b1, 0.f);
      }
  }
  __syncthreads();

  // layer 2 via MFMA: wave wv owns boards wv*16..+15; 32 neurons x2 heads,
  // K=64; B-fragments built inline from pw2/vw2.
  {
    f32x4 acc2[2][2];  // [head][ntile]
#pragma unroll
    for (int h = 0; h < 2; ++h)
#pragma unroll
      for (int t = 0; t < 2; ++t)
#pragma unroll
        for (int r = 0; r < 4; ++r) acc2[h][t][r] = 0.f;
#pragma unroll
    for (int h = 0; h < 2; ++h) {
      const float* w2 = h ? vw2 : pw2;
#pragma unroll
      for (int k2 = 0; k2 < 2; ++k2) {
        union { u16 s8[8]; short8 v; } afl;
        const float* ap =
            &sh.s2.act[(wv * 16 + lm) * 132 + h * 64 + k2 * 32 + lq * 8];
        f32x4 a0 = *(const f32x4*)ap;
        f32x4 a1 = *(const f32x4*)(ap + 4);
#pragma unroll
        for (int e = 0; e < 4; ++e) {
          afl.s8[e] = f2bf(a0[e]);
          afl.s8[4 + e] = f2bf(a1[e]);
        }
#pragma unroll
        for (int t = 0; t < 2; ++t) {
          union { u16 s8[8]; short8 v; } bfl;
#pragma unroll
          for (int j = 0; j < 8; ++j)
            bfl.s8[j] = f2bf(w2[(k2 * 32 + lq * 8 + j) * 32 + t * 16 + lm]);
          acc2[h][t] = __builtin_amdgcn_mfma_f32_16x16x32_bf16(
              afl.v, bfl.v, acc2[h][t], 0, 0, 0);
        }
      }
    }
#pragma unroll
    for (int h = 0; h < 2; ++h)
#pragma unroll
      for (int t = 0; t < 2; ++t) {
        const float bias = (h ? vb2 : pb2)[t * 16 + lm];
#pragma unroll
        for (int r = 0; r < 4; ++r) {
          int board = wv * 16 + lq * 4 + r;
          sh.s2.p2v2[board * 65 + h * 32 + t * 16 + lm] =
              fmaxf(acc2[h][t][r] + bias, 0.f);
        }
      }
  }
  __syncthreads();

  // layer 3 + softmax / tanh: one thread per board (serial, R5-proven)
  if (tid < TB) {
    const float* pv = &sh.s2.p2v2[tid * 65];
    float lg[7];
#pragma unroll
    for (int j = 0; j < 7; ++j) lg[j] = pb3[j];
    for (int n = 0; n < 32; ++n) {
      float t = pv[n];
#pragma unroll
      for (int j = 0; j < 7; ++j) lg[j] = fmaf(t, pw3[n * 7 + j], lg[j]);
    }
    float mx = lg[0];
#pragma unroll
    for (int j = 1; j < 7; ++j) mx = fmaxf(mx, lg[j]);
    float ex[7], ssum = 0.f;
#pragma unroll
    for (int j = 0; j < 7; ++j) {
      ex[j] = expf(lg[j] - mx);
      ssum += ex[j];
    }
    float inv = 1.f / ssum;
    int bg = bid * TB + tid;
#pragma unroll
    for (int j = 0; j < 7; ++j) out[bg * 7 + j] = ex[j] * inv;
    float va = vb3[0];
#pragma unroll
    for (int n = 0; n < 32; ++n) va = fmaf(pv[32 + n], vw3[n], va);
    out[B_TOTAL * 7 + bg] = tanhf(va);
  }
}

// ---------------------------------------------------------------------------
extern "C" void kernel_launch(void* const* d_in, const int* in_sizes, int n_in,
                              void* d_out, int out_size, void* d_ws, size_t ws_size,
                              hipStream_t stream) {
  const float* x     = (const float*)d_in[0];
  const float* convw = (const float*)d_in[1];
  const float* convb = (const float*)d_in[2];
  const float* gamma = (const float*)d_in[3];
  const float* beta  = (const float*)d_in[4];
  const float* pw1 = (const float*)d_in[5];
  const float* pb1 = (const float*)d_in[6];
  const float* pw2 = (const float*)d_in[7];
  const float* pb2 = (const float*)d_in[8];
  const float* pw3 = (const float*)d_in[9];
  const float* pb3 = (const float*)d_in[10];
  const float* vw1 = (const float*)d_in[11];
  const float* vb1 = (const float*)d_in[12];
  const float* vw2 = (const float*)d_in[13];
  const float* vb2 = (const float*)d_in[14];
  const float* vw3 = (const float*)d_in[15];
  const float* vb3 = (const float*)d_in[16];
  float* out = (float*)d_out;

  float* ws   = (float*)d_ws;
  float* sums = ws;                     // 1806 f32
  int*   ctr  = (int*)(ws + 1806);      // 1 int
  float* AD   = ws + 1808;              // 512 f32
  u16*   Wp   = (u16*)(ws + 2320);      // 393216 bf16, 16B-aligned
  u16*   Wp2  = Wp + 393216;            // 4096 bf16 (unused this round)

  hipMemsetAsync(ws, 0, 1807 * sizeof(float), stream);
  prep_kernel<<<257, 256, 0, stream>>>(x, pw1, vw1, pw2, vw2, convw, convb,
                                       gamma, beta, Wp, Wp2, sums, ctr, AD);
  fused_kernel<<<512, 256, 0, stream>>>(x, convw, AD, Wp, pb1, vb1,
                                        pw2, pb2, pw3, pb3, vw2, vb2, vw3, vb3,
                                        out);
}

// Round 9
// 171.373 us; speedup vs baseline: 9.0523x; 1.0011x over previous
//
#include <hip/hip_runtime.h>
#include <math.h>

#define B_TOTAL 32768
#define TB 64
#define NCH 256
#define EPS 1e-5f

typedef unsigned short u16;
typedef __attribute__((ext_vector_type(8))) short short8;
typedef __attribute__((ext_vector_type(4))) float f32x4;

__device__ __forceinline__ u16 f2bf(float f) {  // RNE
  unsigned int u = __builtin_bit_cast(unsigned int, f);
  u = (u + 0x7fffu + ((u >> 16) & 1u)) >> 16;
  return (u16)u;
}
__device__ __forceinline__ short8 u4s8(uint4 v) {
  return __builtin_bit_cast(short8, v);
}

// ---------------------------------------------------------------------------
// prep (257 blocks) — R8-verbatim (verified passing):
//   0..127   stats: 256 boards each (2 passes), atomicAdd into sums; 128th
//            finisher computes BN-affine A,D inline (T-matrix reduction).
//   128..255 pack [pw1|vw1] -> Wp (bf16 B-fragment order), 384 chunks each.
//   256      pack [pw2|vw2] -> Wp2 (written, unused this round).
// ---------------------------------------------------------------------------
__global__ __launch_bounds__(256) void prep_kernel(
    const float* __restrict__ x, const float* __restrict__ pw1,
    const float* __restrict__ vw1, const float* __restrict__ pw2,
    const float* __restrict__ vw2, const float* __restrict__ convw,
    const float* __restrict__ convb, const float* __restrict__ gamma,
    const float* __restrict__ beta, u16* __restrict__ Wp,
    u16* __restrict__ Wp2, float* __restrict__ sums, int* __restrict__ ctr,
    float* __restrict__ AD) {
  const int tid = threadIdx.x;
  if (blockIdx.x == 256) {
#pragma unroll
    for (int k = 0; k < 2; ++k) {
      const int id = k * 256 + tid;  // < 512
      const int lm = id & 15, lq = (id >> 4) & 3, t = (id >> 6) & 1;
      const int k2 = (id >> 7) & 1, h = (id >> 8) & 1;
      const float* w2 = h ? vw2 : pw2;
      union { u16 s[8]; uint4 v; } pk;
#pragma unroll
      for (int j = 0; j < 8; ++j)
        pk.s[j] = f2bf(w2[(k2 * 32 + lq * 8 + j) * 32 + t * 16 + lm]);
      *(uint4*)&Wp2[(size_t)id * 8] = pk.v;
    }
    return;
  }
  if (blockIdx.x >= 128) {
    const int base = (blockIdx.x - 128) * 384;
#pragma unroll
    for (int k = 0; k < 2; ++k) {
      const int s = k * 256 + tid;
      if (s >= 384) break;
      const int id = base + s;  // < 49152
      const int g = id / 1536;
      const int rem = id - g * 1536;
      const int kt = rem >> 9;
      const int ctl = (rem >> 6) & 7;
      const int lq = (rem >> 4) & 3;
      const int lm = rem & 15;
      const int p = kt * 4 + lq;
      const int col = ctl * 16 + lm;
      union { u16 s[8]; uint4 v; } pk;
#pragma unroll
      for (int j = 0; j < 8; ++j) {
        int r = (g * 8 + j) * 12 + p;
        float w = (col < 64) ? pw1[r * 64 + col] : vw1[r * 64 + (col - 64)];
        pk.s[j] = f2bf(w);
      }
      *(uint4*)&Wp[(size_t)id * 8] = pk.v;
    }
    return;
  }
  // ---- stats branch: 256 boards over 2 passes of 128 ----
  __shared__ float xb[128 * 44];
  __shared__ int elect;
  const int bid = blockIdx.x;
  if (tid < 128) { xb[tid * 44 + 42] = 0.f; xb[tid * 44 + 43] = 0.f; }
  const int ti = tid / 22, tj = tid - (tid / 22) * 22;  // 11 x 22 = 242
  const int i0 = ti * 4, j0 = tj * 2;
  float acc[4][2];
#pragma unroll
  for (int i = 0; i < 4; ++i) { acc[i][0] = 0.f; acc[i][1] = 0.f; }
  float msum = 0.f;
  for (int pass = 0; pass < 2; ++pass) {
    if (pass) __syncthreads();
    const float4* src =
        (const float4*)(x + (size_t)(bid * 2 + pass) * 128 * 42);
    for (int i = tid; i < 1344; i += 256) {
      float4 v = src[i];
      float vals[4] = {v.x, v.y, v.z, v.w};
#pragma unroll
      for (int e = 0; e < 4; ++e) {
        int idx = i * 4 + e;
        int b = idx / 42;
        int pos = idx - b * 42;
        xb[b * 44 + pos] = vals[e];
      }
    }
    __syncthreads();
    if (tid < 242) {
      for (int b = 0; b < 128; ++b) {
        f32x4 va = *(const f32x4*)&xb[b * 44 + i0];
        float2 vb = *(const float2*)&xb[b * 44 + j0];
#pragma unroll
        for (int i = 0; i < 4; ++i) {
          acc[i][0] = fmaf(va[i], vb.x, acc[i][0]);
          acc[i][1] = fmaf(va[i], vb.y, acc[i][1]);
        }
      }
    }
    if (tid < 42) {
      float a = 0.f;
      for (int b = 0; b < 128; ++b) a += xb[b * 44 + tid];
      msum += a;
    }
  }
  if (tid < 242) {
#pragma unroll
    for (int i = 0; i < 4; ++i)
#pragma unroll
      for (int j = 0; j < 2; ++j) {
        int gi = i0 + i, gj = j0 + j;
        if (gi < 42 && gj < 42) atomicAdd(&sums[42 + gi * 42 + gj], acc[i][j]);
      }
  }
  if (tid < 42) atomicAdd(&sums[tid], msum);
  __threadfence();
  __syncthreads();
  if (tid == 0) {
    int old = __hip_atomic_fetch_add(ctr, 1, __ATOMIC_ACQ_REL,
                                     __HIP_MEMORY_SCOPE_AGENT);
    elect = (old == 127);
  }
  __syncthreads();
  if (!elect) return;

  // ---- inline stats2 (only the 128th-finishing block) ----
  float* sM = xb;           // 42
  float* sS = xb + 42;      // 42*42
  float* T = xb + 1806;     // 16*16
  float* M16 = xb + 2062;   // 16
  const float invB = 1.f / (float)B_TOTAL;
  for (int idx = tid; idx < 1806; idx += 256) {
    float v = __hip_atomic_load(&sums[idx], __ATOMIC_RELAXED,
                                __HIP_MEMORY_SCOPE_AGENT) * invB;
    if (idx < 42) sM[idx] = v; else sS[idx - 42] = v;
  }
  __syncthreads();
  {
    const int k = tid >> 4, k2 = tid & 15;
    float s = 0.f;
#pragma unroll
    for (int p = 0; p < 12; ++p) {
      int pi = p >> 2, pj = p & 3;
      int i1 = (pi + (k >> 2)) * 7 + pj + (k & 3);
      int i2 = (pi + (k2 >> 2)) * 7 + pj + (k2 & 3);
      s += sS[i1 * 42 + i2];
    }
    T[tid] = s;
    if (tid < 16) {
      float m = 0.f;
#pragma unroll
      for (int p = 0; p < 12; ++p) {
        int pi = p >> 2, pj = p & 3;
        m += sM[(pi + (tid >> 2)) * 7 + pj + (tid & 3)];
      }
      M16[tid] = m;
    }
  }
  __syncthreads();
  {
    float w[16];
#pragma unroll
    for (int k = 0; k < 16; ++k) w[k] = convw[tid * 16 + k];
    const float cb = convb[tid];
    float accm = 0.f, q = 0.f;
#pragma unroll
    for (int k = 0; k < 16; ++k) {
      accm = fmaf(w[k], M16[k], accm);
      float t = 0.f;
#pragma unroll
      for (int k2 = 0; k2 < 16; ++k2) t = fmaf(w[k2], T[k * 16 + k2], t);
      q = fmaf(w[k], t, q);
    }
    const float meanY = cb + accm * (1.f / 12.f);
    const float EY2 = cb * cb + (2.f * cb * accm + q) * (1.f / 12.f);
    float var = EY2 - meanY * meanY;
    var = fmaxf(var, 0.f);
    const float alpha = gamma[tid] * rsqrtf(var + EPS);
    AD[tid] = alpha;
    AD[NCH + tid] = beta[tid] + alpha * (cb - meanY);
  }
}

// ---------------------------------------------------------------------------
// fused — R8 + pieces D and E ONLY (bisection round):
//   D: S1 = {ADs; union{Bpatch,Apk0}; union{boards,Apk1}} (51200 B) + one
//      extra barrier after bp[] loads (Apk0 aliases Bpatch).
//   E: __launch_bounds__(256, 3)  -> 3 blocks/CU.
// Layer-2 inline w2 frags and serial layer-3 stay R8-verbatim.
// ---------------------------------------------------------------------------
struct S1 {
  float ADs[512];                                            // 2048 B
  union { u16 Bpatch[12288]; u16 Apk0[12288]; } a;           // 24576 B
  union { float boards[TB * 43]; u16 Apk1[12288]; } b;       // 24576 B
};
struct S2 {
  float act[TB * 132];
  float p2v2[TB * 65];
};
union Sh { S1 s1; S2 s2; };

__global__ __launch_bounds__(256, 3) void fused_kernel(
    const float* __restrict__ x, const float* __restrict__ convw,
    const float* __restrict__ AD, const u16* __restrict__ Wp,
    const float* __restrict__ pb1, const float* __restrict__ vb1,
    const float* __restrict__ pw2, const float* __restrict__ pb2,
    const float* __restrict__ pw3, const float* __restrict__ pb3,
    const float* __restrict__ vw2, const float* __restrict__ vb2,
    const float* __restrict__ vw3, const float* __restrict__ vb3,
    float* __restrict__ out) {
  __shared__ Sh sh;
  const int tid = threadIdx.x;
  const int bid = blockIdx.x;
  const int l = tid & 63, wv = tid >> 6;
  const int lm = l & 15, lq = l >> 4;
  const uint4* Wp4 = (const uint4*)Wp;

  // stage boards into padded LDS (region later reused as Apk1)
  {
    const float4* src = (const float4*)(x + (size_t)bid * (TB * 42));
    for (int i = tid; i < (TB * 42) / 4; i += 256) {
      float4 v = src[i];
      float vals[4] = {v.x, v.y, v.z, v.w};
#pragma unroll
      for (int e = 0; e < 4; ++e) {
        int idx = i * 4 + e;
        int b = idx / 42;
        int pos = idx - b * 42;
        sh.s1.b.boards[b * 43 + pos] = vals[e];
      }
    }
  }
  sh.s1.ADs[tid] = AD[tid];
  sh.s1.ADs[256 + tid] = AD[256 + tid];
  __syncthreads();

  // build conv patch B-fragments in LDS (once)
#pragma unroll
  for (int i = 0; i < 6; ++i) {
    int s = i * 256 + tid;
    int plm = s & 15, lq2 = (s >> 4) & 1, nt = s >> 5;
    int p = nt >> 2, b = ((nt & 3) << 4) | plm;
    int pi = p >> 2, pj = p & 3;
    const float* bd = &sh.s1.b.boards[b * 43 + (pi + lq2 * 2) * 7 + pj];
    union { u16 s8[8]; uint4 q; } pk;
#pragma unroll
    for (int d = 0; d < 4; ++d) {
      pk.s8[d] = f2bf(bd[d]);
      pk.s8[4 + d] = f2bf(bd[7 + d]);
    }
    *(uint4*)&sh.s1.a.Bpatch[(size_t)((nt * 2 + lq2) * 16 + plm) * 8] = pk.q;
  }
  __syncthreads();  // Bpatch ready; boards consumed

  // patch fragments -> registers (gp-invariant). lq>=2 duplicates lq&1 rows
  // (finite data; multiplied by zero A-weights).
  uint4 bp[12];
#pragma unroll
  for (int i = 0; i < 12; ++i) {
    int nt = i * 4 + wv;
    bp[i] = *(const uint4*)&sh.s1.a.Bpatch[(size_t)((nt * 2 + (lq & 1)) * 16 + lm) * 8];
  }
  __syncthreads();  // all bp reads done; Apk0 (=Bpatch) region free

  f32x4 acc[4][2];
#pragma unroll
  for (int R = 0; R < 4; ++R)
#pragma unroll
    for (int t = 0; t < 2; ++t)
#pragma unroll
      for (int r = 0; r < 4; ++r) acc[R][t][r] = 0.f;

  const int parw = lq >> 1, hw = lq & 1;
  char* const apk0 = (char*)sh.s1.a.Apk0;
  char* const apk1 = (char*)sh.s1.b.Apk1;

  // conv for group-pair gp into buffer: 16 channels, K=16 live of K=32
#define CONV_STEP(gp_, wbuf_)                                                  \
  {                                                                            \
    const int chan = (gp_)*16 + lm;                                            \
    union { u16 s8[8]; short8 v; } aw;                                         \
    if (lq < 2) {                                                              \
      const float* wsrc = convw + chan * 16 + lq * 8;                          \
      _Pragma("unroll") for (int t2 = 0; t2 < 8; ++t2) aw.s8[t2] =             \
          f2bf(wsrc[t2]);                                                      \
    } else {                                                                   \
      _Pragma("unroll") for (int t2 = 0; t2 < 8; ++t2) aw.s8[t2] = 0;          \
    }                                                                          \
    const f32x4 A4 = *(const f32x4*)&sh.s1.ADs[(gp_)*16 + lq * 4];             \
    const f32x4 D4 = *(const f32x4*)&sh.s1.ADs[256 + (gp_)*16 + lq * 4];       \
    _Pragma("unroll") for (int i = 0; i < 12; ++i) {                           \
      const int nt = i * 4 + wv;                                               \
      f32x4 c = {0.f, 0.f, 0.f, 0.f};                                          \
      c = __builtin_amdgcn_mfma_f32_16x16x32_bf16(aw.v, u4s8(bp[i]), c, 0, 0,  \
                                                  0);                          \
      union { u16 s4[4]; uint2 q; } hp;                                        \
      _Pragma("unroll") for (int r = 0; r < 4; ++r) hp.s4[r] =                 \
          f2bf(fmaxf(fmaf(c[r], A4[r], D4[r]), 0.f));                          \
      const int K_ = nt >> 4, kq_ = (nt >> 2) & 3, R_ = nt & 3;                \
      const int off = ((parw * 3 + K_) * 4 + R_) * 1024 +                      \
                      (kq_ * 16 + lm) * 16 + hw * 8;                           \
      *(uint2*)((wbuf_) + off) = hp.q;                                         \
    }                                                                          \
  }

  CONV_STEP(0, apk0);

#pragma unroll 1
  for (int gp = 0; gp < 16; ++gp) {
    __syncthreads();  // Apk[gp&1] written; prev GEMM done with Apk[(gp+1)&1]

    // B fragments for this gp from L2 (lane-linear, coalesced)
    uint4 Bv[12];
#pragma unroll
    for (int par = 0; par < 2; ++par)
#pragma unroll
      for (int K = 0; K < 3; ++K)
#pragma unroll
        for (int t = 0; t < 2; ++t)
          Bv[par * 6 + K * 2 + t] =
              Wp4[(size_t)(2 * gp + par) * 1536 + K * 512 + (wv * 2 + t) * 64 + l];

    // conv for next group-pair into the other buffer (overlaps GEMM below)
    if (gp < 15) {
      char* wbuf = ((gp + 1) & 1) ? apk1 : apk0;
      CONV_STEP(gp + 1, wbuf);
    }

    // GEMM for gp from Apk[gp&1]
    const char* rbuf = (gp & 1) ? apk1 : apk0;
#pragma unroll
    for (int par = 0; par < 2; ++par)
#pragma unroll
      for (int K = 0; K < 3; ++K) {
        short8 af[4];
#pragma unroll
        for (int R = 0; R < 4; ++R)
          af[R] = *(const short8*)(rbuf + ((par * 3 + K) * 4 + R) * 1024 +
                                   l * 16);
#pragma unroll
        for (int R = 0; R < 4; ++R) {
          acc[R][0] = __builtin_amdgcn_mfma_f32_16x16x32_bf16(
              af[R], u4s8(Bv[par * 6 + K * 2 + 0]), acc[R][0], 0, 0, 0);
          acc[R][1] = __builtin_amdgcn_mfma_f32_16x16x32_bf16(
              af[R], u4s8(Bv[par * 6 + K * 2 + 1]), acc[R][1], 0, 0, 0);
        }
      }
  }
  __syncthreads();  // all GEMM reads done; LDS reused as S2

  // epilogue: bias + relu -> act LDS (cols 0..63 policy, 64..127 value)
  {
    const int n0 = wv * 32 + lm;
    const int n1 = n0 + 16;
    const float b0 = (n0 < 64) ? pb1[n0] : vb1[n0 - 64];
    const float b1 = (n1 < 64) ? pb1[n1] : vb1[n1 - 64];
#pragma unroll
    for (int R = 0; R < 4; ++R)
#pragma unroll
      for (int r = 0; r < 4; ++r) {
        int row = R * 16 + lq * 4 + r;
        sh.s2.act[row * 132 + n0] = fmaxf(acc[R][0][r] + b0, 0.f);
        sh.s2.act[row * 132 + n1] = fmaxf(acc[R][1][r] + b1, 0.f);
      }
  }
  __syncthreads();

  // layer 2 via MFMA: wave wv owns boards wv*16..+15; 32 neurons x2 heads,
  // K=64; B-fragments built inline from pw2/vw2 (R8-verbatim).
  {
    f32x4 acc2[2][2];  // [head][ntile]
#pragma unroll
    for (int h = 0; h < 2; ++h)
#pragma unroll
      for (int t = 0; t < 2; ++t)
#pragma unroll
        for (int r = 0; r < 4; ++r) acc2[h][t][r] = 0.f;
#pragma unroll
    for (int h = 0; h < 2; ++h) {
      const float* w2 = h ? vw2 : pw2;
#pragma unroll
      for (int k2 = 0; k2 < 2; ++k2) {
        union { u16 s8[8]; short8 v; } afl;
        const float* ap =
            &sh.s2.act[(wv * 16 + lm) * 132 + h * 64 + k2 * 32 + lq * 8];
        f32x4 a0 = *(const f32x4*)ap;
        f32x4 a1 = *(const f32x4*)(ap + 4);
#pragma unroll
        for (int e = 0; e < 4; ++e) {
          afl.s8[e] = f2bf(a0[e]);
          afl.s8[4 + e] = f2bf(a1[e]);
        }
#pragma unroll
        for (int t = 0; t < 2; ++t) {
          union { u16 s8[8]; short8 v; } bfl;
#pragma unroll
          for (int j = 0; j < 8; ++j)
            bfl.s8[j] = f2bf(w2[(k2 * 32 + lq * 8 + j) * 32 + t * 16 + lm]);
          acc2[h][t] = __builtin_amdgcn_mfma_f32_16x16x32_bf16(
              afl.v, bfl.v, acc2[h][t], 0, 0, 0);
        }
      }
    }
#pragma unroll
    for (int h = 0; h < 2; ++h)
#pragma unroll
      for (int t = 0; t < 2; ++t) {
        const float bias = (h ? vb2 : pb2)[t * 16 + lm];
#pragma unroll
        for (int r = 0; r < 4; ++r) {
          int board = wv * 16 + lq * 4 + r;
          sh.s2.p2v2[board * 65 + h * 32 + t * 16 + lm] =
              fmaxf(acc2[h][t][r] + bias, 0.f);
        }
      }
  }
  __syncthreads();

  // layer 3 + softmax / tanh: one thread per board (serial, R8-verbatim)
  if (tid < TB) {
    const float* pv = &sh.s2.p2v2[tid * 65];
    float lg[7];
#pragma unroll
    for (int j = 0; j < 7; ++j) lg[j] = pb3[j];
    for (int n = 0; n < 32; ++n) {
      float t = pv[n];
#pragma unroll
      for (int j = 0; j < 7; ++j) lg[j] = fmaf(t, pw3[n * 7 + j], lg[j]);
    }
    float mx = lg[0];
#pragma unroll
    for (int j = 1; j < 7; ++j) mx = fmaxf(mx, lg[j]);
    float ex[7], ssum = 0.f;
#pragma unroll
    for (int j = 0; j < 7; ++j) {
      ex[j] = expf(lg[j] - mx);
      ssum += ex[j];
    }
    float inv = 1.f / ssum;
    int bg = bid * TB + tid;
#pragma unroll
    for (int j = 0; j < 7; ++j) out[bg * 7 + j] = ex[j] * inv;
    float va = vb3[0];
#pragma unroll
    for (int n = 0; n < 32; ++n) va = fmaf(pv[32 + n], vw3[n], va);
    out[B_TOTAL * 7 + bg] = tanhf(va);
  }
}

// ---------------------------------------------------------------------------
extern "C" void kernel_launch(void* const* d_in, const int* in_sizes, int n_in,
                              void* d_out, int out_size, void* d_ws, size_t ws_size,
                              hipStream_t stream) {
  const float* x     = (const float*)d_in[0];
  const float* convw = (const float*)d_in[1];
  const float* convb = (const float*)d_in[2];
  const float* gamma = (const float*)d_in[3];
  const float* beta  = (const float*)d_in[4];
  const float* pw1 = (const float*)d_in[5];
  const float* pb1 = (const float*)d_in[6];
  const float* pw2 = (const float*)d_in[7];
  const float* pb2 = (const float*)d_in[8];
  const float* pw3 = (const float*)d_in[9];
  const float* pb3 = (const float*)d_in[10];
  const float* vw1 = (const float*)d_in[11];
  const float* vb1 = (const float*)d_in[12];
  const float* vw2 = (const float*)d_in[13];
  const float* vb2 = (const float*)d_in[14];
  const float* vw3 = (const float*)d_in[15];
  const float* vb3 = (const float*)d_in[16];
  float* out = (float*)d_out;

  float* ws   = (float*)d_ws;
  float* sums = ws;                     // 1806 f32
  int*   ctr  = (int*)(ws + 1806);      // 1 int
  float* AD   = ws + 1808;              // 512 f32
  u16*   Wp   = (u16*)(ws + 2320);      // 393216 bf16, 16B-aligned
  u16*   Wp2  = Wp + 393216;            // 4096 bf16 (unused this round)

  hipMemsetAsync(ws, 0, 1807 * sizeof(float), stream);
  prep_kernel<<<257, 256, 0, stream>>>(x, pw1, vw1, pw2, vw2, convw, convb,
                                       gamma, beta, Wp, Wp2, sums, ctr, AD);
  fused_kernel<<<512, 256, 0, stream>>>(x, convw, AD, Wp, pb1, vb1,
                                        pw2, pb2, pw3, pb3, vw2, vb2, vw3, vb3,
                                        out);
}